// Round 1
// baseline (886.179 us; speedup 1.0000x reference)
//
#include <hip/hip_runtime.h>
#include <cstdint>
#include <cstddef>

// Problem constants (match reference):
//   B=64, T_D=256, T_P=1024, D=128, MAX_LEN=1024, NEG=-1e9
#define NEGV -1e9f
constexpr int Bq = 64;
constexpr int TDc = 256;
constexpr int TPc = 1024;

// ---------------------------------------------------------------------------
// Linear projection: Out[t, d] = sum_k X[t,k] * W[d,k] + b[d]
// Block: 256 threads computes 64 tokens x 32 out-dims. K=128 fully in LDS.
// Grid: (ntok/64, 128/32)
// ---------------------------------------------------------------------------
__global__ __launch_bounds__(256) void proj_kernel(
    const float* __restrict__ X, const float* __restrict__ W,
    const float* __restrict__ bias, float* __restrict__ Out) {
  __shared__ float Xs[64][132];   // stride 132 floats = 528B (16B aligned, conflict-tame)
  __shared__ float Ws[32][132];
  const int t0 = blockIdx.x * 64;
  const int d0 = blockIdx.y * 32;
  const int tid = threadIdx.x;

  // Stage X tile (64x128 contiguous tokens) and W tile (32x128 contiguous rows)
  {
    const float4* src = (const float4*)(X + (size_t)t0 * 128);
#pragma unroll
    for (int r = 0; r < 8; ++r) {
      int i4 = tid + 256 * r;            // 0..2047 float4s
      int t = i4 >> 5, k4 = i4 & 31;
      *(float4*)&Xs[t][k4 * 4] = src[i4];
    }
    const float4* wsrc = (const float4*)(W + (size_t)d0 * 128);
#pragma unroll
    for (int r = 0; r < 4; ++r) {
      int i4 = tid + 256 * r;            // 0..1023
      int d = i4 >> 5, k4 = i4 & 31;
      *(float4*)&Ws[d][k4 * 4] = wsrc[i4];
    }
  }
  __syncthreads();

  const int d_loc = tid & 31;
  const int tg = tid >> 5;               // 8 token groups of 8
  float acc[8] = {0.f, 0.f, 0.f, 0.f, 0.f, 0.f, 0.f, 0.f};
#pragma unroll 4
  for (int k = 0; k < 128; k += 4) {
    float4 wv = *(const float4*)&Ws[d_loc][k];
#pragma unroll
    for (int s = 0; s < 8; ++s) {
      float4 xv = *(const float4*)&Xs[tg * 8 + s][k];
      acc[s] += wv.x * xv.x;
      acc[s] += wv.y * xv.y;
      acc[s] += wv.z * xv.z;
      acc[s] += wv.w * xv.w;
    }
  }
  float bb = bias[d0 + d_loc];
#pragma unroll
  for (int s = 0; s < 8; ++s) {
    Out[(size_t)(t0 + tg * 8 + s) * 128 + d0 + d_loc] = acc[s] + bb;
  }
}

// ---------------------------------------------------------------------------
// Column max of K over seq axis: part[b,c,d] = max over chunk-of-j K[b,j,d]
// 128 threads (one per d). Grid (B, nchunks).
// ---------------------------------------------------------------------------
__global__ void colmax_part_kernel(const float* __restrict__ K,
                                   float* __restrict__ part, int Tj, int chunk) {
  int b = blockIdx.x, c = blockIdx.y, d = threadIdx.x;
  const float* p = K + ((size_t)b * Tj + (size_t)c * chunk) * 128 + d;
  float m = -3.4e38f;
  for (int j = 0; j < chunk; ++j) m = fmaxf(m, p[(size_t)j * 128]);
  part[((size_t)b * gridDim.y + c) * 128 + d] = m;
}

// out[b*128+d] = max over c part[b,c,d]. idx grid over B*128.
__global__ void maxreduce_kernel(const float* __restrict__ part,
                                 float* __restrict__ out, int nc) {
  int idx = blockIdx.x * 256 + threadIdx.x;
  int b = idx >> 7, d = idx & 127;
  float m = -3.4e38f;
  for (int c = 0; c < nc; ++c) m = fmaxf(m, part[((size_t)b * nc + c) * 128 + d]);
  out[idx] = m;
}

// ---------------------------------------------------------------------------
// In-place: K = exp(K - maxK[b,d]); V = K_exp * V. float4 elementwise.
// ---------------------------------------------------------------------------
__global__ void expk_kernel(float4* __restrict__ K4, float4* __restrict__ V4,
                            const float* __restrict__ mx, int Tj) {
  size_t i4 = (size_t)blockIdx.x * 256 + threadIdx.x;
  size_t total = (size_t)Bq * Tj * 32;
  if (i4 >= total) return;
  int d4 = (int)(i4 & 31);
  int b = (int)(i4 / ((size_t)Tj * 32));
  float4 m = *(const float4*)(mx + (size_t)b * 128 + d4 * 4);
  float4 k = K4[i4], v = V4[i4];
  k.x = expf(k.x - m.x); k.y = expf(k.y - m.y);
  k.z = expf(k.z - m.z); k.w = expf(k.w - m.w);
  v.x *= k.x; v.y *= k.y; v.z *= k.z; v.w *= k.w;
  K4[i4] = k;
  V4[i4] = v;
}

// ---------------------------------------------------------------------------
// Transpose pos_bias[0:256, 0:1024] (row stride 1024) -> pbT [1024][256]
// Grid (256/32, 1024/32), 256 threads (32x8).
// ---------------------------------------------------------------------------
__global__ void transpose_pb_kernel(const float* __restrict__ pb,
                                    float* __restrict__ pbT) {
  __shared__ float t[32][33];
  int j0 = blockIdx.x * 32, i0 = blockIdx.y * 32;
  int tx = threadIdx.x & 31, ty = threadIdx.x >> 5;
#pragma unroll
  for (int r = 0; r < 32; r += 8)
    t[ty + r][tx] = pb[(size_t)(j0 + ty + r) * 1024 + i0 + tx];
  __syncthreads();
#pragma unroll
  for (int r = 0; r < 32; r += 8)
    pbT[(size_t)(i0 + ty + r) * 256 + j0 + tx] = t[tx][ty + r];
}

// ---------------------------------------------------------------------------
// maxPB[b,i] = max_j ( (qmask[b,i] && kmask[b,j]) ? PB[i,j] : NEG )
// One wave (64 lanes) per (b,i); 4 waves per block.
// ---------------------------------------------------------------------------
template <int TJ>
__global__ void maxpb_kernel(const float* __restrict__ PB, int pb_stride,
                             const int* __restrict__ qmask,
                             const int* __restrict__ kmask,
                             float* __restrict__ maxPB, int Ti) {
  int w = blockIdx.x * 4 + (threadIdx.x >> 6);
  int lane = threadIdx.x & 63;
  int b = w / Ti, i = w - b * Ti;
  int qm = qmask[b * Ti + i];
  float m = NEGV;
#pragma unroll
  for (int j = lane; j < TJ; j += 64) {
    float v = (qm && kmask[b * TJ + j]) ? PB[(size_t)i * pb_stride + j] : NEGV;
    m = fmaxf(m, v);
  }
#pragma unroll
  for (int off = 32; off > 0; off >>= 1) m = fmaxf(m, __shfl_down(m, off, 64));
  if (lane == 0) maxPB[b * Ti + i] = m;
}

// ---------------------------------------------------------------------------
// AFT core: per block — one b, 32 query rows i, all 128 dims d.
//   w[i][j] = exp(pb_masked[i][j] - maxPB[b,i])
//   num[i][d] = sum_j w[i][j] * eKV[b,j,d];  den same with eK
//   Y[b,i,d] = sigmoid(Q[b,i,d]) * num/den
// Each thread: 2 i's (iA, iA+16) x 8 contiguous d's. j staged in LDS tiles of 32.
// ---------------------------------------------------------------------------
template <int TJ>
__global__ __launch_bounds__(256) void aft_kernel(
    const float* __restrict__ Q, const float* __restrict__ eK,
    const float* __restrict__ eKV, const float* __restrict__ PB, int pb_stride,
    const int* __restrict__ qmask, const int* __restrict__ kmask,
    const float* __restrict__ maxPB, float* __restrict__ Y, int Ti) {
  __shared__ float ek[32][128];
  __shared__ float ekv[32][128];
  __shared__ float wls[32][33];
  __shared__ float mpb[32];
  __shared__ int qms[32];

  const int b = blockIdx.y;
  const int i0 = blockIdx.x * 32;
  const int tid = threadIdx.x;

  if (tid < 32) {
    mpb[tid] = maxPB[b * Ti + i0 + tid];
    qms[tid] = qmask[b * Ti + i0 + tid];
  }

  const int iA = tid >> 4;            // 0..15
  const int d0 = (tid & 15) * 8;      // 0..120
  float num0[8] = {0}, den0[8] = {0}, num1[8] = {0}, den1[8] = {0};

  for (int jt = 0; jt < TJ; jt += 32) {
    __syncthreads();  // protects LDS from previous tile's readers (and covers init)
    const float4* gk = (const float4*)(eK + ((size_t)b * TJ + jt) * 128);
    const float4* gkv = (const float4*)(eKV + ((size_t)b * TJ + jt) * 128);
#pragma unroll
    for (int r = 0; r < 4; ++r) {
      int i4 = tid + 256 * r;  // 0..1023 float4s of the 32x128 tile
      int j = i4 >> 5, k4 = i4 & 31;
      *(float4*)&ek[j][k4 * 4] = gk[i4];
      *(float4*)&ekv[j][k4 * 4] = gkv[i4];
    }
#pragma unroll
    for (int r = 0; r < 4; ++r) {
      int idx = tid + 256 * r;  // 0..1023 = 32 i x 32 j
      int il = idx >> 5, jj = idx & 31;
      float pb = PB[(size_t)(i0 + il) * pb_stride + jt + jj];
      float pbm = ((idx < 32 ? 1 : 1) && qms[il] && kmask[b * TJ + jt + jj]) ? pb : NEGV;
      wls[il][jj] = __expf(pbm - mpb[il]);
    }
    __syncthreads();
#pragma unroll 8
    for (int j = 0; j < 32; ++j) {
      float w0 = wls[iA][j];
      float w1 = wls[iA + 16][j];
      float4 ka = *(const float4*)&ek[j][d0];
      float4 kb = *(const float4*)&ek[j][d0 + 4];
      float4 va = *(const float4*)&ekv[j][d0];
      float4 vb = *(const float4*)&ekv[j][d0 + 4];
      num0[0] += w0 * va.x; num0[1] += w0 * va.y; num0[2] += w0 * va.z; num0[3] += w0 * va.w;
      num0[4] += w0 * vb.x; num0[5] += w0 * vb.y; num0[6] += w0 * vb.z; num0[7] += w0 * vb.w;
      den0[0] += w0 * ka.x; den0[1] += w0 * ka.y; den0[2] += w0 * ka.z; den0[3] += w0 * ka.w;
      den0[4] += w0 * kb.x; den0[5] += w0 * kb.y; den0[6] += w0 * kb.z; den0[7] += w0 * kb.w;
      num1[0] += w1 * va.x; num1[1] += w1 * va.y; num1[2] += w1 * va.z; num1[3] += w1 * va.w;
      num1[4] += w1 * vb.x; num1[5] += w1 * vb.y; num1[6] += w1 * vb.z; num1[7] += w1 * vb.w;
      den1[0] += w1 * ka.x; den1[1] += w1 * ka.y; den1[2] += w1 * ka.z; den1[3] += w1 * ka.w;
      den1[4] += w1 * kb.x; den1[5] += w1 * kb.y; den1[6] += w1 * kb.z; den1[7] += w1 * kb.w;
    }
  }

  size_t base0 = ((size_t)b * Ti + i0 + iA) * 128 + d0;
  size_t base1 = base0 + (size_t)16 * 128;
  float y0[8], y1[8];
#pragma unroll
  for (int dd = 0; dd < 8; ++dd) {
    float q0 = Q[base0 + dd];
    float q1 = Q[base1 + dd];
    y0[dd] = (1.f / (1.f + __expf(-q0))) * num0[dd] / den0[dd];
    y1[dd] = (1.f / (1.f + __expf(-q1))) * num1[dd] / den1[dd];
  }
#pragma unroll
  for (int dd = 0; dd < 8; ++dd) {
    Y[base0 + dd] = y0[dd];
    Y[base1 + dd] = y1[dd];
  }
}

// ---------------------------------------------------------------------------
// Masked row-max partials: part[b,c,d] = max over chunk-of-i (mask? Z[b,i,d]:NEG)
// ---------------------------------------------------------------------------
__global__ void rowmax_part_kernel(const float* __restrict__ Z,
                                   const int* __restrict__ mask,
                                   float* __restrict__ part, int Ti, int chunk) {
  int b = blockIdx.x, c = blockIdx.y, d = threadIdx.x;
  const float* p = Z + ((size_t)b * Ti + (size_t)c * chunk) * 128 + d;
  const int* mk = mask + b * Ti + c * chunk;
  float m = NEGV;
  for (int i = 0; i < chunk; ++i) {
    if (mk[i]) m = fmaxf(m, p[(size_t)i * 128]);
  }
  part[((size_t)b * gridDim.y + c) * 128 + d] = m;
}

// ---------------------------------------------------------------------------
extern "C" void kernel_launch(void* const* d_in, const int* in_sizes, int n_in,
                              void* d_out, int out_size, void* d_ws, size_t ws_size,
                              hipStream_t stream) {
  const float* smiles = (const float*)d_in[0];   // [64,256,128]
  const float* prot   = (const float*)d_in[1];   // [64,1024,128]
  const int* smask = (const int*)d_in[2];        // [64,256]
  const int* pmask = (const int*)d_in[3];        // [64,1024]
  const float* pos_bias = (const float*)d_in[4]; // [1024,1024]
  const float* Wqd = (const float*)d_in[5];  const float* bqd = (const float*)d_in[6];
  const float* Wkp = (const float*)d_in[7];  const float* bkp = (const float*)d_in[8];
  const float* Wvp = (const float*)d_in[9];  const float* bvp = (const float*)d_in[10];
  const float* Wqp = (const float*)d_in[11]; const float* bqp = (const float*)d_in[12];
  const float* Wkd = (const float*)d_in[13]; const float* bkd = (const float*)d_in[14];
  const float* Wvd = (const float*)d_in[15]; const float* bvd = (const float*)d_in[16];
  const float* Wpd = (const float*)d_in[17]; const float* bpd = (const float*)d_in[18];
  const float* Wpp = (const float*)d_in[19]; const float* bpp = (const float*)d_in[20];
  float* out = (float*)d_out;                    // y_d [64,128] then y_p [64,128]

  float* ws = (float*)d_ws;
  float* Qd = ws;                     // 64*256*128  = 2,097,152
  float* Kp = Qd + 2097152;           // 64*1024*128 = 8,388,608
  float* Vp = Kp + 8388608;
  float* Qp = Vp + 8388608;
  float* Kd = Qp + 8388608;           // 2,097,152
  float* Vd = Kd + 2097152;
  float* Yd = Vd + 2097152;
  float* Yp = Yd + 2097152;           // 8,388,608
  float* pbT = Yp + 8388608;          // 1024*256 = 262,144
  float* maxKp = pbT + 262144;        // 64*128 = 8192
  float* maxKd = maxKp + 8192;
  float* maxPBd = maxKd + 8192;       // 64*256 = 16384
  float* maxPBp = maxPBd + 16384;     // 64*1024 = 65536
  float* part = maxPBp + 65536;       // 64*8*128 = 65536

  dim3 blk(256);

  // 1) projections
  proj_kernel<<<dim3(256, 4), blk, 0, stream>>>(smiles, Wqd, bqd, Qd);
  proj_kernel<<<dim3(1024, 4), blk, 0, stream>>>(prot, Wkp, bkp, Kp);
  proj_kernel<<<dim3(1024, 4), blk, 0, stream>>>(prot, Wvp, bvp, Vp);
  proj_kernel<<<dim3(1024, 4), blk, 0, stream>>>(prot, Wqp, bqp, Qp);
  proj_kernel<<<dim3(256, 4), blk, 0, stream>>>(smiles, Wkd, bkd, Kd);
  proj_kernel<<<dim3(256, 4), blk, 0, stream>>>(smiles, Wvd, bvd, Vd);

  // 2) k-max then exp transforms (in place)
  colmax_part_kernel<<<dim3(64, 8), dim3(128), 0, stream>>>(Kp, part, 1024, 128);
  maxreduce_kernel<<<32, 256, 0, stream>>>(part, maxKp, 8);
  colmax_part_kernel<<<dim3(64, 8), dim3(128), 0, stream>>>(Kd, part, 256, 32);
  maxreduce_kernel<<<32, 256, 0, stream>>>(part, maxKd, 8);
  expk_kernel<<<(64 * 1024 * 32) / 256, blk, 0, stream>>>((float4*)Kp, (float4*)Vp, maxKp, 1024);
  expk_kernel<<<(64 * 256 * 32) / 256, blk, 0, stream>>>((float4*)Kd, (float4*)Vd, maxKd, 256);

  // 3) pos-bias transpose + masked row maxima of pos-bias
  transpose_pb_kernel<<<dim3(8, 32), blk, 0, stream>>>(pos_bias, pbT);
  maxpb_kernel<1024><<<64 * 256 / 4, blk, 0, stream>>>(pos_bias, 1024, smask, pmask, maxPBd, 256);
  maxpb_kernel<256><<<64 * 1024 / 4, blk, 0, stream>>>(pbT, 256, pmask, smask, maxPBp, 1024);

  // 4) AFT cores
  aft_kernel<1024><<<dim3(8, 64), blk, 0, stream>>>(Qd, Kp, Vp, pos_bias, 1024,
                                                    smask, pmask, maxPBd, Yd, 256);
  aft_kernel<256><<<dim3(32, 64), blk, 0, stream>>>(Qp, Kd, Vd, pbT, 256,
                                                    pmask, smask, maxPBp, Yp, 1024);

  // 5) final projections (reuse Qd/Qp as Z buffers — Q no longer needed)
  proj_kernel<<<dim3(256, 4), blk, 0, stream>>>(Yd, Wpd, bpd, Qd);
  proj_kernel<<<dim3(1024, 4), blk, 0, stream>>>(Yp, Wpp, bpp, Qp);

  // 6) masked row-max -> outputs
  rowmax_part_kernel<<<dim3(64, 8), dim3(128), 0, stream>>>(Qd, smask, part, 256, 32);
  maxreduce_kernel<<<32, 256, 0, stream>>>(part, out, 8);
  rowmax_part_kernel<<<dim3(64, 8), dim3(128), 0, stream>>>(Qp, pmask, part, 1024, 128);
  maxreduce_kernel<<<32, 256, 0, stream>>>(part, out + 8192, 8);
}

// Round 2
// 441.004 us; speedup vs baseline: 2.0095x; 2.0095x over previous
//
#include <hip/hip_runtime.h>
#include <cstdint>
#include <cstddef>

#define NEGV -1e9f
constexpr int Bq = 64;

typedef __bf16 bf16x8 __attribute__((ext_vector_type(8)));
typedef float f32x4 __attribute__((ext_vector_type(4)));
typedef unsigned short us4 __attribute__((ext_vector_type(4)));
typedef unsigned short us8 __attribute__((ext_vector_type(8)));

__device__ inline unsigned short f2bf(float f) {
  unsigned int u = __float_as_uint(f);
  u += 0x7fffu + ((u >> 16) & 1u);   // round-to-nearest-even
  return (unsigned short)(u >> 16);
}

// ---------------------------------------------------------------------------
// MFMA projection: Out[t,d] = sum_k X[t,k]*W[d,k] + b[d].  K=128, N=128.
// Block 256 thr (4 waves). Tile 64 t x 128 d. Grid: ntok/64.
// A = X (staged bf16 in LDS, row stride 136 us = 272B -> 2-way banks = free),
// B = W rows from global (fp32 -> bf16 in-register; W is L2-resident).
// ---------------------------------------------------------------------------
__global__ __launch_bounds__(256) void proj_mfma(
    const float* __restrict__ X, const float* __restrict__ W,
    const float* __restrict__ bias, float* __restrict__ Out) {
  __shared__ unsigned short xL[64 * 136];
  const int t0 = blockIdx.x * 64;
  const int tid = threadIdx.x;

#pragma unroll
  for (int r = 0; r < 8; ++r) {
    int i4 = tid + 256 * r;              // 2048 float4s = 64x128
    int t = i4 >> 5, k4 = (i4 & 31) * 4;
    float4 v = *(const float4*)&X[(size_t)(t0 + t) * 128 + k4];
    us4 p;
    p.x = f2bf(v.x); p.y = f2bf(v.y); p.z = f2bf(v.z); p.w = f2bf(v.w);
    *(us4*)&xL[t * 136 + k4] = p;
  }
  __syncthreads();

  const int lane = tid & 63, wave = tid >> 6;
  const int lo = lane & 15, hi = lane >> 4;
  const int d0 = wave * 32;

  f32x4 acc[4][2];
#pragma unroll
  for (int a = 0; a < 4; ++a)
#pragma unroll
    for (int s = 0; s < 2; ++s)
#pragma unroll
      for (int r = 0; r < 4; ++r) acc[a][s][r] = 0.f;

#pragma unroll
  for (int kt = 0; kt < 128; kt += 32) {
    bf16x8 bw[2];
#pragma unroll
    for (int s = 0; s < 2; ++s) {
      const float* wp = &W[(size_t)(d0 + s * 16 + lo) * 128 + kt + hi * 8];
      float4 w0 = *(const float4*)wp;
      float4 w1 = *(const float4*)(wp + 4);
      us8 t;
      t[0] = f2bf(w0.x); t[1] = f2bf(w0.y); t[2] = f2bf(w0.z); t[3] = f2bf(w0.w);
      t[4] = f2bf(w1.x); t[5] = f2bf(w1.y); t[6] = f2bf(w1.z); t[7] = f2bf(w1.w);
      bw[s] = __builtin_bit_cast(bf16x8, t);
    }
#pragma unroll
    for (int a = 0; a < 4; ++a) {
      bf16x8 af = *(const bf16x8*)&xL[(a * 16 + lo) * 136 + kt + hi * 8];
#pragma unroll
      for (int s = 0; s < 2; ++s)
        acc[a][s] = __builtin_amdgcn_mfma_f32_16x16x32_bf16(af, bw[s], acc[a][s], 0, 0, 0);
    }
  }

#pragma unroll
  for (int s = 0; s < 2; ++s) {
    int d = d0 + s * 16 + lo;
    float bb = bias[d];
#pragma unroll
    for (int a = 0; a < 4; ++a)
#pragma unroll
      for (int r = 0; r < 4; ++r) {
        int t = t0 + a * 16 + hi * 4 + r;
        Out[(size_t)t * 128 + d] = acc[a][s][r] + bb;
      }
  }
}

// ---------------------------------------------------------------------------
// Column max of K over seq axis (fp32).
// ---------------------------------------------------------------------------
__global__ void colmax_part_kernel(const float* __restrict__ K,
                                   float* __restrict__ part, int Tj, int chunk) {
  int b = blockIdx.x, c = blockIdx.y, d = threadIdx.x;
  const float* p = K + ((size_t)b * Tj + (size_t)c * chunk) * 128 + d;
  float m = -3.4e38f;
  for (int j = 0; j < chunk; ++j) m = fmaxf(m, p[(size_t)j * 128]);
  part[((size_t)b * gridDim.y + c) * 128 + d] = m;
}

__global__ void maxreduce_kernel(const float* __restrict__ part,
                                 float* __restrict__ out, int nc) {
  int idx = blockIdx.x * 256 + threadIdx.x;
  int b = idx >> 7, d = idx & 127;
  float m = -3.4e38f;
  for (int c = 0; c < nc; ++c) m = fmaxf(m, part[((size_t)b * nc + c) * 128 + d]);
  out[idx] = m;
}

// ---------------------------------------------------------------------------
// expk + transpose: eKT[b][d][j] = bf16(exp(K[b][j][d]-maxK[b][d])),
//                   eKVT[b][d][j] = bf16(exp(..)*V[b][j][d]).
// Block 256 thr handles (b, 64 j) x 128 d. LDS transpose, stride 72 us (144B).
// ---------------------------------------------------------------------------
template <int TJ>
__global__ __launch_bounds__(256) void expk_t(
    const float* __restrict__ K, const float* __restrict__ V,
    const float* __restrict__ mx, unsigned short* __restrict__ eKT,
    unsigned short* __restrict__ eKVT) {
  __shared__ unsigned short ekL[128 * 72];
  __shared__ unsigned short ekvL[128 * 72];
  const int b = blockIdx.y, j0 = blockIdx.x * 64, tid = threadIdx.x;

#pragma unroll
  for (int r = 0; r < 8; ++r) {
    int i4 = tid + 256 * r;              // 2048 float4s = 64j x 128d
    int j = i4 >> 5, d4 = (i4 & 31) * 4;
    size_t g = ((size_t)(b * TJ + j0 + j)) * 128 + d4;
    float4 k = *(const float4*)&K[g];
    float4 v = *(const float4*)&V[g];
    float4 m = *(const float4*)&mx[b * 128 + d4];
    float e0 = __expf(k.x - m.x), e1 = __expf(k.y - m.y);
    float e2 = __expf(k.z - m.z), e3 = __expf(k.w - m.w);
    ekL[(d4 + 0) * 72 + j] = f2bf(e0);
    ekL[(d4 + 1) * 72 + j] = f2bf(e1);
    ekL[(d4 + 2) * 72 + j] = f2bf(e2);
    ekL[(d4 + 3) * 72 + j] = f2bf(e3);
    ekvL[(d4 + 0) * 72 + j] = f2bf(e0 * v.x);
    ekvL[(d4 + 1) * 72 + j] = f2bf(e1 * v.y);
    ekvL[(d4 + 2) * 72 + j] = f2bf(e2 * v.z);
    ekvL[(d4 + 3) * 72 + j] = f2bf(e3 * v.w);
  }
  __syncthreads();
#pragma unroll
  for (int r = 0; r < 8; ++r) {
    int q = tid + 256 * r;               // 2048 16B-chunks (2 arrays)
    int arr = q >> 10, qq = q & 1023;
    int d = qq >> 3, cc = qq & 7;
    us8 val = *(const us8*)&(arr ? ekvL : ekL)[d * 72 + cc * 8];
    unsigned short* dst = arr ? eKVT : eKT;
    *(us8*)&dst[((size_t)b * 128 + d) * TJ + j0 + cc * 8] = val;
  }
}

// ---------------------------------------------------------------------------
// Transpose pos_bias[0:256,0:1024] -> pbT[1024][256]
// ---------------------------------------------------------------------------
__global__ void transpose_pb_kernel(const float* __restrict__ pb,
                                    float* __restrict__ pbT) {
  __shared__ float t[32][33];
  int j0 = blockIdx.x * 32, i0 = blockIdx.y * 32;
  int tx = threadIdx.x & 31, ty = threadIdx.x >> 5;
#pragma unroll
  for (int r = 0; r < 32; r += 8)
    t[ty + r][tx] = pb[(size_t)(j0 + ty + r) * 1024 + i0 + tx];
  __syncthreads();
#pragma unroll
  for (int r = 0; r < 32; r += 8)
    pbT[(size_t)(i0 + ty + r) * 256 + j0 + tx] = t[tx][ty + r];
}

// ---------------------------------------------------------------------------
// maxPB[b,i] = max_j masked PB.  One wave per (b,i).
// ---------------------------------------------------------------------------
template <int TJ>
__global__ void maxpb_kernel(const float* __restrict__ PB, int pb_stride,
                             const int* __restrict__ qmask,
                             const int* __restrict__ kmask,
                             float* __restrict__ maxPB, int Ti) {
  int w = blockIdx.x * 4 + (threadIdx.x >> 6);
  int lane = threadIdx.x & 63;
  int b = w / Ti, i = w - b * Ti;
  int qm = qmask[b * Ti + i];
  float m = NEGV;
#pragma unroll
  for (int j = lane; j < TJ; j += 64) {
    float v = (qm && kmask[b * TJ + j]) ? PB[(size_t)i * pb_stride + j] : NEGV;
    m = fmaxf(m, v);
  }
#pragma unroll
  for (int off = 32; off > 0; off >>= 1) m = fmaxf(m, __shfl_down(m, off, 64));
  if (lane == 0) maxPB[b * Ti + i] = m;
}

// ---------------------------------------------------------------------------
// MFMA AFT core. Block 256 thr (4 waves): one b, 32 i rows, 128 d.
// Per K-step (32 j): stage eKT/eKVT tiles [128d][32j] bf16 into LDS
// (row stride 40 us = 80B -> 2-way banks), compute W=exp(pb-maxPB) bf16
// A-tile [32i][32j].  Wave w owns d0=w*32: 2 d-subtiles x 2 i-subtiles
// x {num,den} = 8 MFMA per K-step sharing A-frags.
// ---------------------------------------------------------------------------
template <int TJ>
__global__ __launch_bounds__(256) void aft_mfma(
    const float* __restrict__ Q, const unsigned short* __restrict__ eKT,
    const unsigned short* __restrict__ eKVT, const float* __restrict__ PB,
    int pb_stride, const int* __restrict__ qmask,
    const int* __restrict__ kmask, const float* __restrict__ maxPB,
    float* __restrict__ Y, int Ti) {
  __shared__ unsigned short ekL[128 * 40];
  __shared__ unsigned short ekvL[128 * 40];
  __shared__ unsigned short wL[32 * 40];
  __shared__ float mpb[32];
  __shared__ int qms[32];

  const int b = blockIdx.y;
  const int i0 = blockIdx.x * 32;
  const int tid = threadIdx.x;
  if (tid < 32) {
    mpb[tid] = maxPB[b * Ti + i0 + tid];
    qms[tid] = qmask[b * Ti + i0 + tid];
  }

  const int lane = tid & 63, wave = tid >> 6;
  const int lo = lane & 15, hi = lane >> 4;
  const int d0 = wave * 32;
  const int il = tid >> 3, j4 = (tid & 7) * 4;

  f32x4 accN[2][2], accD[2][2];
#pragma unroll
  for (int a = 0; a < 2; ++a)
#pragma unroll
    for (int s = 0; s < 2; ++s)
#pragma unroll
      for (int r = 0; r < 4; ++r) { accN[a][s][r] = 0.f; accD[a][s][r] = 0.f; }

  for (int jt = 0; jt < TJ; jt += 32) {
    __syncthreads();
    // stage eKT/eKVT tile: 512 16B-chunks each
#pragma unroll
    for (int r = 0; r < 2; ++r) {
      int q = tid + 256 * r;
      int d = q >> 2, cc = q & 3;
      size_t g = ((size_t)b * 128 + d) * TJ + jt + cc * 8;
      *(us8*)&ekL[d * 40 + cc * 8] = *(const us8*)&eKT[g];
      *(us8*)&ekvL[d * 40 + cc * 8] = *(const us8*)&eKVT[g];
    }
    // W tile: 32 i x 32 j, 4 values per thread
    {
      float4 pb = *(const float4*)&PB[(size_t)(i0 + il) * pb_stride + jt + j4];
      int4 km = *(const int4*)&kmask[b * TJ + jt + j4];
      int qm = qms[il];
      float m = mpb[il];
      us4 wv;
      wv.x = f2bf(__expf(((qm && km.x) ? pb.x : NEGV) - m));
      wv.y = f2bf(__expf(((qm && km.y) ? pb.y : NEGV) - m));
      wv.z = f2bf(__expf(((qm && km.z) ? pb.z : NEGV) - m));
      wv.w = f2bf(__expf(((qm && km.w) ? pb.w : NEGV) - m));
      *(us4*)&wL[il * 40 + j4] = wv;
    }
    __syncthreads();

    bf16x8 af[2], bk[2], bv[2];
#pragma unroll
    for (int a = 0; a < 2; ++a)
      af[a] = *(const bf16x8*)&wL[(a * 16 + lo) * 40 + hi * 8];
#pragma unroll
    for (int s = 0; s < 2; ++s) {
      int row = d0 + s * 16 + lo;
      bk[s] = *(const bf16x8*)&ekL[row * 40 + hi * 8];
      bv[s] = *(const bf16x8*)&ekvL[row * 40 + hi * 8];
    }
#pragma unroll
    for (int a = 0; a < 2; ++a)
#pragma unroll
      for (int s = 0; s < 2; ++s) {
        accN[a][s] = __builtin_amdgcn_mfma_f32_16x16x32_bf16(af[a], bv[s], accN[a][s], 0, 0, 0);
        accD[a][s] = __builtin_amdgcn_mfma_f32_16x16x32_bf16(af[a], bk[s], accD[a][s], 0, 0, 0);
      }
  }

#pragma unroll
  for (int a = 0; a < 2; ++a)
#pragma unroll
    for (int s = 0; s < 2; ++s)
#pragma unroll
      for (int r = 0; r < 4; ++r) {
        int i = i0 + a * 16 + hi * 4 + r;
        int d = d0 + s * 16 + lo;
        size_t off = ((size_t)b * Ti + i) * 128 + d;
        float q = Q[off];
        float sg = 1.f / (1.f + __expf(-q));
        Y[off] = sg * accN[a][s][r] / accD[a][s][r];
      }
}

// ---------------------------------------------------------------------------
// Masked row-max partials over final projection output.
// ---------------------------------------------------------------------------
__global__ void rowmax_part_kernel(const float* __restrict__ Z,
                                   const int* __restrict__ mask,
                                   float* __restrict__ part, int Ti, int chunk) {
  int b = blockIdx.x, c = blockIdx.y, d = threadIdx.x;
  const float* p = Z + ((size_t)b * Ti + (size_t)c * chunk) * 128 + d;
  const int* mk = mask + b * Ti + c * chunk;
  float m = NEGV;
  for (int i = 0; i < chunk; ++i) {
    if (mk[i]) m = fmaxf(m, p[(size_t)i * 128]);
  }
  part[((size_t)b * gridDim.y + c) * 128 + d] = m;
}

// ---------------------------------------------------------------------------
extern "C" void kernel_launch(void* const* d_in, const int* in_sizes, int n_in,
                              void* d_out, int out_size, void* d_ws, size_t ws_size,
                              hipStream_t stream) {
  const float* smiles = (const float*)d_in[0];
  const float* prot   = (const float*)d_in[1];
  const int* smask = (const int*)d_in[2];
  const int* pmask = (const int*)d_in[3];
  const float* pos_bias = (const float*)d_in[4];
  const float* Wqd = (const float*)d_in[5];  const float* bqd = (const float*)d_in[6];
  const float* Wkp = (const float*)d_in[7];  const float* bkp = (const float*)d_in[8];
  const float* Wvp = (const float*)d_in[9];  const float* bvp = (const float*)d_in[10];
  const float* Wqp = (const float*)d_in[11]; const float* bqp = (const float*)d_in[12];
  const float* Wkd = (const float*)d_in[13]; const float* bkd = (const float*)d_in[14];
  const float* Wvd = (const float*)d_in[15]; const float* bvd = (const float*)d_in[16];
  const float* Wpd = (const float*)d_in[17]; const float* bpd = (const float*)d_in[18];
  const float* Wpp = (const float*)d_in[19]; const float* bpp = (const float*)d_in[20];
  float* out = (float*)d_out;

  // Workspace layout (floats). Same total footprint as round 1 (fits ws).
  float* ws = (float*)d_ws;
  float* A = ws;                 // Qd               2,097,152
  float* Bf = A + 2097152;       // Kp -> (later) Yp 8,388,608
  float* C = Bf + 8388608;       // Vp -> eKTd/eKVTd 8,388,608
  float* Dd = C + 8388608;       // Qp -> Zp         8,388,608
  float* E = Dd + 8388608;       // Kd               2,097,152
  float* F = E + 2097152;        // Vd               2,097,152
  float* G = F + 2097152;        // Yd               2,097,152
  float* H = G + 2097152;        // eKTp/eKVTp       8,388,608
  float* pbT = H + 8388608;      // 262,144
  float* maxKp = pbT + 262144;   // 8192
  float* maxKd = maxKp + 8192;   // 8192
  float* maxPBd = maxKd + 8192;  // 16384
  float* maxPBp = maxPBd + 16384;// 65536
  float* part = maxPBp + 65536;  // 65536

  unsigned short* eKTp = (unsigned short*)H;
  unsigned short* eKVTp = eKTp + 8388608;   // = H + 4,194,304 floats
  unsigned short* eKTd = (unsigned short*)C;
  unsigned short* eKVTd = eKTd + 2097152;

  dim3 blk(256);

  // 1) input projections (bf16 MFMA)
  proj_mfma<<<256, blk, 0, stream>>>(smiles, Wqd, bqd, A);
  proj_mfma<<<1024, blk, 0, stream>>>(prot, Wkp, bkp, Bf);
  proj_mfma<<<1024, blk, 0, stream>>>(prot, Wvp, bvp, C);
  proj_mfma<<<1024, blk, 0, stream>>>(prot, Wqp, bqp, Dd);
  proj_mfma<<<256, blk, 0, stream>>>(smiles, Wkd, bkd, E);
  proj_mfma<<<256, blk, 0, stream>>>(smiles, Wvd, bvd, F);

  // 2) per-(b,d) K max, then exp+transpose to bf16
  colmax_part_kernel<<<dim3(64, 8), dim3(128), 0, stream>>>(Bf, part, 1024, 128);
  maxreduce_kernel<<<32, 256, 0, stream>>>(part, maxKp, 8);
  colmax_part_kernel<<<dim3(64, 8), dim3(128), 0, stream>>>(E, part, 256, 32);
  maxreduce_kernel<<<32, 256, 0, stream>>>(part, maxKd, 8);
  expk_t<1024><<<dim3(16, 64), blk, 0, stream>>>(Bf, C, maxKp, eKTp, eKVTp);
  expk_t<256><<<dim3(4, 64), blk, 0, stream>>>(E, F, maxKd, eKTd, eKVTd);

  // 3) pos-bias transpose + masked row maxima
  transpose_pb_kernel<<<dim3(8, 32), blk, 0, stream>>>(pos_bias, pbT);
  maxpb_kernel<1024><<<64 * 256 / 4, blk, 0, stream>>>(pos_bias, 1024, smask, pmask, maxPBd, 256);
  maxpb_kernel<256><<<64 * 1024 / 4, blk, 0, stream>>>(pbT, 256, pmask, smask, maxPBp, 1024);

  // 4) AFT cores (bf16 MFMA)
  aft_mfma<1024><<<dim3(8, 64), blk, 0, stream>>>(A, eKTp, eKVTp, pos_bias, 1024,
                                                  smask, pmask, maxPBd, G, 256);
  aft_mfma<256><<<dim3(32, 64), blk, 0, stream>>>(Dd, eKTd, eKVTd, pbT, 256,
                                                  pmask, smask, maxPBp, Bf, 1024);

  // 5) final projections (A, Dd are dead -> reuse as outputs)
  proj_mfma<<<256, blk, 0, stream>>>(G, Wpd, bpd, A);
  proj_mfma<<<1024, blk, 0, stream>>>(Bf, Wpp, bpp, Dd);

  // 6) masked row-max -> outputs
  rowmax_part_kernel<<<dim3(64, 8), dim3(128), 0, stream>>>(A, smask, part, 256, 32);
  maxreduce_kernel<<<32, 256, 0, stream>>>(part, out, 8);
  rowmax_part_kernel<<<dim3(64, 8), dim3(128), 0, stream>>>(Dd, pmask, part, 1024, 128);
  maxreduce_kernel<<<32, 256, 0, stream>>>(part, out + 8192, 8);
}

// Round 3
// 268.571 us; speedup vs baseline: 3.2996x; 1.6420x over previous
//
#include <hip/hip_runtime.h>
#include <cstdint>
#include <cstddef>

#define NEGV -1e9f

typedef __bf16 bf16x8 __attribute__((ext_vector_type(8)));
typedef float f32x4 __attribute__((ext_vector_type(4)));
typedef unsigned short us4 __attribute__((ext_vector_type(4)));
typedef unsigned short us8 __attribute__((ext_vector_type(8)));

__device__ __forceinline__ unsigned short f2bf(float f) {
  unsigned int u = __float_as_uint(f);
  u += 0x7fffu + ((u >> 16) & 1u);   // round-to-nearest-even
  return (unsigned short)(u >> 16);
}

// async 16B global -> LDS (dest = lds base + lane*16)
__device__ __forceinline__ void gld16(const void* g, void* l) {
  __builtin_amdgcn_global_load_lds(
      (const __attribute__((address_space(1))) unsigned int*)g,
      (__attribute__((address_space(3))) unsigned int*)l, 16, 0, 0);
}

// ---------------------------------------------------------------------------
// epb[i][j] = bf16(exp(pos_bias[i][j])), i<256, j<1024 (row stride 1024)
// epbT[j][i] = same, transposed.  Grid 256 blocks x 256 thr, 32x32 tiles.
// ---------------------------------------------------------------------------
__global__ void epb_kernel(const float* __restrict__ pb,
                           unsigned short* __restrict__ epb,
                           unsigned short* __restrict__ epbT) {
  __shared__ unsigned short t[32][33];
  const int j0 = (blockIdx.x & 31) * 32, i0 = (blockIdx.x >> 5) * 32;
  const int tx = threadIdx.x & 31, ty = threadIdx.x >> 5;
#pragma unroll
  for (int r = 0; r < 4; ++r) {
    int i = i0 + ty + r * 8;
    unsigned short u = f2bf(__expf(pb[(size_t)i * 1024 + j0 + tx]));
    epb[(size_t)i * 1024 + j0 + tx] = u;
    t[ty + r * 8][tx] = u;
  }
  __syncthreads();
#pragma unroll
  for (int r = 0; r < 4; ++r)
    epbT[(size_t)(j0 + ty + r * 8) * 256 + i0 + tx] = t[tx][ty + r * 8];
}

// ---------------------------------------------------------------------------
// Fused Q/K/V projection per side:
//   sigQ[t,d]  = sigmoid(X@Wq^T + bq)                (fp32, row-major)
//   eKT[b,d,t] = bf16( mask[t] ? exp(X@Wk^T + bk) : 0 )     (transposed)
//   eKVT       = eKT * (X@Wv^T + bv)                        (transposed)
// Block: 64 tokens x 128 d, 256 thr (4 waves, wave = 64t x 32d).
// ---------------------------------------------------------------------------
__global__ __launch_bounds__(256) void proj3(
    const float* __restrict__ X, const int* __restrict__ mask,
    const float* __restrict__ Wq, const float* __restrict__ bq,
    const float* __restrict__ Wk, const float* __restrict__ bk_,
    const float* __restrict__ Wv, const float* __restrict__ bv,
    float* __restrict__ sigQ, unsigned short* __restrict__ eKT,
    unsigned short* __restrict__ eKVT, int T) {
  __shared__ unsigned short smem[2 * 128 * 72];  // 36864 us; xL aliases front
  unsigned short* xL = smem;                     // 64*136 = 8704 us
  const int tid = threadIdx.x;
  const int g0 = blockIdx.x * 64;                // global token base
  const int b = g0 / T;
  const int tl0 = g0 - b * T;

#pragma unroll
  for (int r = 0; r < 8; ++r) {
    int i4 = tid + 256 * r;                      // 2048 float4 = 64x128
    int t = i4 >> 5, k4 = (i4 & 31) * 4;
    float4 v = *(const float4*)&X[(size_t)(g0 + t) * 128 + k4];
    us4 p;
    p.x = f2bf(v.x); p.y = f2bf(v.y); p.z = f2bf(v.z); p.w = f2bf(v.w);
    *(us4*)&xL[t * 136 + k4] = p;
  }
  __syncthreads();

  const int lane = tid & 63, wave = tid >> 6;
  const int lo = lane & 15, hi = lane >> 4;
  const int d0 = wave * 32;

  f32x4 aQ[4][2], aK[4][2], aV[4][2];
#pragma unroll
  for (int a = 0; a < 4; ++a)
#pragma unroll
    for (int s = 0; s < 2; ++s)
#pragma unroll
      for (int r = 0; r < 4; ++r) { aQ[a][s][r] = 0.f; aK[a][s][r] = 0.f; aV[a][s][r] = 0.f; }

#pragma unroll
  for (int kt = 0; kt < 128; kt += 32) {
    bf16x8 bQ[2], bK[2], bV[2];
#pragma unroll
    for (int s = 0; s < 2; ++s) {
      size_t roff = (size_t)(d0 + s * 16 + lo) * 128 + kt + hi * 8;
      {
        float4 w0 = *(const float4*)&Wq[roff];
        float4 w1 = *(const float4*)&Wq[roff + 4];
        us8 t; t[0]=f2bf(w0.x); t[1]=f2bf(w0.y); t[2]=f2bf(w0.z); t[3]=f2bf(w0.w);
        t[4]=f2bf(w1.x); t[5]=f2bf(w1.y); t[6]=f2bf(w1.z); t[7]=f2bf(w1.w);
        bQ[s] = __builtin_bit_cast(bf16x8, t);
      }
      {
        float4 w0 = *(const float4*)&Wk[roff];
        float4 w1 = *(const float4*)&Wk[roff + 4];
        us8 t; t[0]=f2bf(w0.x); t[1]=f2bf(w0.y); t[2]=f2bf(w0.z); t[3]=f2bf(w0.w);
        t[4]=f2bf(w1.x); t[5]=f2bf(w1.y); t[6]=f2bf(w1.z); t[7]=f2bf(w1.w);
        bK[s] = __builtin_bit_cast(bf16x8, t);
      }
      {
        float4 w0 = *(const float4*)&Wv[roff];
        float4 w1 = *(const float4*)&Wv[roff + 4];
        us8 t; t[0]=f2bf(w0.x); t[1]=f2bf(w0.y); t[2]=f2bf(w0.z); t[3]=f2bf(w0.w);
        t[4]=f2bf(w1.x); t[5]=f2bf(w1.y); t[6]=f2bf(w1.z); t[7]=f2bf(w1.w);
        bV[s] = __builtin_bit_cast(bf16x8, t);
      }
    }
#pragma unroll
    for (int a = 0; a < 4; ++a) {
      bf16x8 af = *(const bf16x8*)&xL[(a * 16 + lo) * 136 + kt + hi * 8];
#pragma unroll
      for (int s = 0; s < 2; ++s) {
        aQ[a][s] = __builtin_amdgcn_mfma_f32_16x16x32_bf16(af, bQ[s], aQ[a][s], 0, 0, 0);
        aK[a][s] = __builtin_amdgcn_mfma_f32_16x16x32_bf16(af, bK[s], aK[a][s], 0, 0, 0);
        aV[a][s] = __builtin_amdgcn_mfma_f32_16x16x32_bf16(af, bV[s], aV[a][s], 0, 0, 0);
      }
    }
  }

  // Q epilogue: sigmoid, direct store
#pragma unroll
  for (int s = 0; s < 2; ++s) {
    int d = d0 + s * 16 + lo;
    float bb = bq[d];
#pragma unroll
    for (int a = 0; a < 4; ++a)
#pragma unroll
      for (int r = 0; r < 4; ++r) {
        int t = g0 + a * 16 + hi * 4 + r;
        float q = aQ[a][s][r] + bb;
        sigQ[(size_t)t * 128 + d] = 1.f / (1.f + __expf(-q));
      }
  }

  __syncthreads();  // all xL reads done; reuse smem for transpose
  unsigned short* ekL = smem;           // [128][72]
  unsigned short* ekvL = smem + 9216;   // [128][72]
#pragma unroll
  for (int s = 0; s < 2; ++s) {
    int d = d0 + s * 16 + lo;
    float bbk = bk_[d], bbv = bv[d];
#pragma unroll
    for (int a = 0; a < 4; ++a)
#pragma unroll
      for (int r = 0; r < 4; ++r) {
        int tl = a * 16 + hi * 4 + r;    // 0..63
        int mk = mask[g0 + tl];
        float ek = mk ? __expf(aK[a][s][r] + bbk) : 0.f;
        float ekv = ek * (aV[a][s][r] + bbv);
        ekL[d * 72 + tl] = f2bf(ek);
        ekvL[d * 72 + tl] = f2bf(ekv);
      }
  }
  __syncthreads();
#pragma unroll
  for (int r = 0; r < 8; ++r) {
    int q = tid + 256 * r;               // 2048 chunks: 2 arrays x 128d x 8
    int arr = q >> 10, qq = q & 1023;
    int d = qq >> 3, c = qq & 7;
    us8 v = *(const us8*)&smem[arr * 9216 + d * 72 + c * 8];
    unsigned short* dst = arr ? eKVT : eKT;
    *(us8*)&dst[((size_t)b * 128 + d) * T + tl0 + c * 8] = v;
  }
}

// ---------------------------------------------------------------------------
// Unified AFT GEMM (both sides in one launch).
//   num[b,i,d] = sum_j epb[i,j] * eKVT[b,d,j];  den with eKT
//   Y[b,i,d] = bf16( sigQ[b,i,d] * num/den )
// Block tile 128i x 128d (4 waves 2x2, wave 64i x 64d). K-step 64 j.
// B tiles (eKT/eKVT) via global_load_lds, XOR-swizzled (2-way banks only).
// A frags (epb, L2-hot 512KB) direct global->VGPR.
// Blocks [0,128): drug side (TJ=1024); [128,640): protein side (TJ=256).
// ---------------------------------------------------------------------------
__global__ __launch_bounds__(256, 2) void aft_all(
    const unsigned short* __restrict__ epb, const unsigned short* __restrict__ epbT,
    const unsigned short* __restrict__ eKTd, const unsigned short* __restrict__ eKVTd,
    const unsigned short* __restrict__ eKTp, const unsigned short* __restrict__ eKVTp,
    const float* __restrict__ sigQd, const float* __restrict__ sigQp,
    unsigned short* __restrict__ Yd, unsigned short* __restrict__ Yp) {
  __shared__ unsigned short bkL[128 * 64];   // [d][64j] swizzled, 16 KB
  __shared__ unsigned short bvL[128 * 64];

  const int blk = blockIdx.x;
  const unsigned short *Ap, *KT, *VT;
  const float* SQ;
  unsigned short* Y;
  int b, i0, TJ, Ti, astr;
  if (blk < 128) {  // drug queries over protein keys
    b = blk >> 1; i0 = (blk & 1) * 128; TJ = 1024; Ti = 256;
    Ap = epb; astr = 1024; KT = eKTp; VT = eKVTp; SQ = sigQd; Y = Yd;
  } else {          // protein queries over drug keys
    int k = blk - 128;
    b = k >> 3; i0 = (k & 7) * 128; TJ = 256; Ti = 1024;
    Ap = epbT; astr = 256; KT = eKTd; VT = eKVTd; SQ = sigQp; Y = Yp;
  }

  const int tid = threadIdx.x, lane = tid & 63, w = tid >> 6;
  const int lo = lane & 15, hi = lane >> 4;
  const int wi = (w >> 1) * 64, wd = (w & 1) * 64;
  const unsigned short* KTb = KT + (size_t)b * 128 * TJ;
  const unsigned short* VTb = VT + (size_t)b * 128 * TJ;
  const int slotbase = w * 256;   // this wave's 256 of 1024 tile chunks

  f32x4 aN[4][4], aD[4][4];
#pragma unroll
  for (int a = 0; a < 4; ++a)
#pragma unroll
    for (int n = 0; n < 4; ++n)
#pragma unroll
      for (int r = 0; r < 4; ++r) { aN[a][n][r] = 0.f; aD[a][n][r] = 0.f; }

  for (int jt = 0; jt < TJ; jt += 64) {
    __syncthreads();   // previous tile's reads complete
#pragma unroll
    for (int it = 0; it < 4; ++it) {
      int slot = slotbase + it * 64 + lane;
      int r = slot >> 3, sc = slot & 7;
      int cg = sc ^ (r & 7);                       // XOR swizzle
      size_t goff = (size_t)r * TJ + jt + cg * 8;  // us offset
      gld16(KTb + goff, &bkL[(slotbase + it * 64) * 8]);
      gld16(VTb + goff, &bvL[(slotbase + it * 64) * 8]);
    }
    bf16x8 af[4][2];
#pragma unroll
    for (int a = 0; a < 4; ++a)
#pragma unroll
      for (int kt = 0; kt < 2; ++kt)
        af[a][kt] = *(const bf16x8*)
            &Ap[(size_t)(i0 + wi + a * 16 + lo) * astr + jt + kt * 32 + hi * 8];
    __syncthreads();   // drains vmcnt -> LDS tiles + af ready
#pragma unroll
    for (int kt = 0; kt < 2; ++kt) {
      bf16x8 bk[4], bv[4];
#pragma unroll
      for (int n = 0; n < 4; ++n) {
        int row = wd + n * 16 + lo;
        int sc = ((kt * 4 + hi) ^ (row & 7)) * 8;
        bk[n] = *(const bf16x8*)&bkL[row * 64 + sc];
        bv[n] = *(const bf16x8*)&bvL[row * 64 + sc];
      }
#pragma unroll
      for (int a = 0; a < 4; ++a)
#pragma unroll
        for (int n = 0; n < 4; ++n) {
          aN[a][n] = __builtin_amdgcn_mfma_f32_16x16x32_bf16(af[a][kt], bv[n], aN[a][n], 0, 0, 0);
          aD[a][n] = __builtin_amdgcn_mfma_f32_16x16x32_bf16(af[a][kt], bk[n], aD[a][n], 0, 0, 0);
        }
    }
  }

#pragma unroll
  for (int a = 0; a < 4; ++a)
#pragma unroll
    for (int n = 0; n < 4; ++n) {
      int i = i0 + wi + a * 16 + hi * 4;
      int d = wd + n * 16 + lo;
#pragma unroll
      for (int r = 0; r < 4; ++r) {
        size_t off = ((size_t)b * Ti + i + r) * 128 + d;
        float s = SQ[off];
        float y = s * __fdividef(aN[a][n][r], aD[a][n][r]);
        Y[off] = f2bf(y);
      }
    }
}

// ---------------------------------------------------------------------------
// Final projection, bf16 input: Out[t,d] = sum_k Ybf[t,k]*W[d,k] + b[d] (fp32)
// ---------------------------------------------------------------------------
__global__ __launch_bounds__(256) void proj_bf(
    const unsigned short* __restrict__ Xbf, const float* __restrict__ W,
    const float* __restrict__ bias, float* __restrict__ Out) {
  __shared__ unsigned short xL[64 * 136];
  const int t0 = blockIdx.x * 64, tid = threadIdx.x;
#pragma unroll
  for (int r = 0; r < 4; ++r) {
    int c = tid + 256 * r;                 // 1024 us8 chunks
    int t = c >> 4, k8 = (c & 15) * 8;
    *(us8*)&xL[t * 136 + k8] = *(const us8*)&Xbf[(size_t)(t0 + t) * 128 + k8];
  }
  __syncthreads();

  const int lane = tid & 63, wave = tid >> 6;
  const int lo = lane & 15, hi = lane >> 4;
  const int d0 = wave * 32;

  f32x4 acc[4][2];
#pragma unroll
  for (int a = 0; a < 4; ++a)
#pragma unroll
    for (int s = 0; s < 2; ++s)
#pragma unroll
      for (int r = 0; r < 4; ++r) acc[a][s][r] = 0.f;

#pragma unroll
  for (int kt = 0; kt < 128; kt += 32) {
    bf16x8 bw[2];
#pragma unroll
    for (int s = 0; s < 2; ++s) {
      const float* wp = &W[(size_t)(d0 + s * 16 + lo) * 128 + kt + hi * 8];
      float4 w0 = *(const float4*)wp;
      float4 w1 = *(const float4*)(wp + 4);
      us8 t; t[0]=f2bf(w0.x); t[1]=f2bf(w0.y); t[2]=f2bf(w0.z); t[3]=f2bf(w0.w);
      t[4]=f2bf(w1.x); t[5]=f2bf(w1.y); t[6]=f2bf(w1.z); t[7]=f2bf(w1.w);
      bw[s] = __builtin_bit_cast(bf16x8, t);
    }
#pragma unroll
    for (int a = 0; a < 4; ++a) {
      bf16x8 af = *(const bf16x8*)&xL[(a * 16 + lo) * 136 + kt + hi * 8];
#pragma unroll
      for (int s = 0; s < 2; ++s)
        acc[a][s] = __builtin_amdgcn_mfma_f32_16x16x32_bf16(af, bw[s], acc[a][s], 0, 0, 0);
    }
  }

#pragma unroll
  for (int s = 0; s < 2; ++s) {
    int d = d0 + s * 16 + lo;
    float bb = bias[d];
#pragma unroll
    for (int a = 0; a < 4; ++a)
#pragma unroll
      for (int r = 0; r < 4; ++r) {
        int t = t0 + a * 16 + hi * 4 + r;
        Out[(size_t)t * 128 + d] = acc[a][s][r] + bb;
      }
  }
}

// ---------------------------------------------------------------------------
__global__ void rowmax_part_kernel(const float* __restrict__ Z,
                                   const int* __restrict__ mask,
                                   float* __restrict__ part, int Ti, int chunk) {
  int b = blockIdx.x, c = blockIdx.y, d = threadIdx.x;
  const float* p = Z + ((size_t)b * Ti + (size_t)c * chunk) * 128 + d;
  const int* mk = mask + b * Ti + c * chunk;
  float m = NEGV;
  for (int i = 0; i < chunk; ++i) {
    if (mk[i]) m = fmaxf(m, p[(size_t)i * 128]);
  }
  part[((size_t)b * gridDim.y + c) * 128 + d] = m;
}

__global__ void maxreduce_kernel(const float* __restrict__ part,
                                 float* __restrict__ out, int nc) {
  int idx = blockIdx.x * 256 + threadIdx.x;
  int b = idx >> 7, d = idx & 127;
  float m = NEGV;
  for (int c = 0; c < nc; ++c) m = fmaxf(m, part[((size_t)b * nc + c) * 128 + d]);
  out[idx] = m;
}

// ---------------------------------------------------------------------------
extern "C" void kernel_launch(void* const* d_in, const int* in_sizes, int n_in,
                              void* d_out, int out_size, void* d_ws, size_t ws_size,
                              hipStream_t stream) {
  const float* smiles = (const float*)d_in[0];
  const float* prot   = (const float*)d_in[1];
  const int* smask = (const int*)d_in[2];
  const int* pmask = (const int*)d_in[3];
  const float* pos_bias = (const float*)d_in[4];
  const float* Wqd = (const float*)d_in[5];  const float* bqd = (const float*)d_in[6];
  const float* Wkp = (const float*)d_in[7];  const float* bkp = (const float*)d_in[8];
  const float* Wvp = (const float*)d_in[9];  const float* bvp = (const float*)d_in[10];
  const float* Wqp = (const float*)d_in[11]; const float* bqp = (const float*)d_in[12];
  const float* Wkd = (const float*)d_in[13]; const float* bkd = (const float*)d_in[14];
  const float* Wvd = (const float*)d_in[15]; const float* bvd = (const float*)d_in[16];
  const float* Wpd = (const float*)d_in[17]; const float* bpd = (const float*)d_in[18];
  const float* Wpp = (const float*)d_in[19]; const float* bpp = (const float*)d_in[20];
  float* out = (float*)d_out;

  // Workspace (float units)
  float* ws = (float*)d_ws;
  float* sigQd = ws;                       // 2,097,152
  float* sigQp = sigQd + 2097152;          // 8,388,608
  float* Zd    = sigQp + 8388608;          // 2,097,152
  float* Zp    = Zd + 2097152;             // 8,388,608
  float* f0    = Zp + 8388608;
  unsigned short* eKTp  = (unsigned short*)f0;          // 8,388,608 us
  unsigned short* eKVTp = eKTp + 8388608;               // 8,388,608 us
  unsigned short* eKTd  = eKVTp + 8388608;              // 2,097,152 us
  unsigned short* eKVTd = eKTd + 2097152;               // 2,097,152 us
  unsigned short* Yd    = eKVTd + 2097152;              // 2,097,152 us
  unsigned short* Yp    = Yd + 2097152;                 // 8,388,608 us
  unsigned short* epb_  = Yp + 8388608;                 // 262,144 us
  unsigned short* epbT_ = epb_ + 262144;                // 262,144 us
  float* part = (float*)(epbT_ + 262144);               // 65,536 f

  dim3 blk(256);

  // 1) exp(pos_bias) tables (batch-independent)
  epb_kernel<<<256, blk, 0, stream>>>(pos_bias, epb_, epbT_);

  // 2) fused Q/K/V projections (sigmoid(Q) fp32; masked exp'd K/KV bf16 transposed)
  proj3<<<256, blk, 0, stream>>>(smiles, smask, Wqd, bqd, Wkd, bkd, Wvd, bvd,
                                 sigQd, eKTd, eKVTd, 256);
  proj3<<<1024, blk, 0, stream>>>(prot, pmask, Wqp, bqp, Wkp, bkp, Wvp, bvp,
                                  sigQp, eKTp, eKVTp, 1024);

  // 3) unified AFT GEMM (both sides)
  aft_all<<<640, blk, 0, stream>>>(epb_, epbT_, eKTd, eKVTd, eKTp, eKVTp,
                                   sigQd, sigQp, Yd, Yp);

  // 4) final projections (bf16 input)
  proj_bf<<<256, blk, 0, stream>>>(Yd, Wpd, bpd, Zd);
  proj_bf<<<1024, blk, 0, stream>>>(Yp, Wpp, bpp, Zp);

  // 5) masked row-max -> outputs
  rowmax_part_kernel<<<dim3(64, 8), dim3(128), 0, stream>>>(Zd, smask, part, 256, 32);
  maxreduce_kernel<<<32, blk, 0, stream>>>(part, out, 8);
  rowmax_part_kernel<<<dim3(64, 8), dim3(128), 0, stream>>>(Zp, pmask, part, 1024, 128);
  maxreduce_kernel<<<32, blk, 0, stream>>>(part, out + 8192, 8);
}

// Round 4
// 207.193 us; speedup vs baseline: 4.2771x; 1.2962x over previous
//
#include <hip/hip_runtime.h>
#include <cstdint>
#include <cstddef>

#define NEGV -1e9f

typedef __bf16 bf16x8 __attribute__((ext_vector_type(8)));
typedef float f32x4 __attribute__((ext_vector_type(4)));
typedef unsigned short us4 __attribute__((ext_vector_type(4)));
typedef unsigned short us8 __attribute__((ext_vector_type(8)));

__device__ __forceinline__ unsigned short f2bf(float f) {
  unsigned int u = __float_as_uint(f);
  u += 0x7fffu + ((u >> 16) & 1u);   // round-to-nearest-even
  return (unsigned short)(u >> 16);
}
__device__ __forceinline__ float bf2f(unsigned short u) {
  return __uint_as_float(((unsigned)u) << 16);
}

// async 16B global -> LDS (dest = wave-uniform base + lane*16)
__device__ __forceinline__ void gld16(const void* g, void* l) {
  __builtin_amdgcn_global_load_lds(
      (const __attribute__((address_space(1))) unsigned int*)g,
      (__attribute__((address_space(3))) unsigned int*)l, 16, 0, 0);
}

// ---------------------------------------------------------------------------
// Convert the 8 weight matrices (128x128 f32 each) to bf16 once.
// Grid (16, 8) x 256 thr; each thread converts one float4.
// ---------------------------------------------------------------------------
__global__ void wcvt_kernel(const float* __restrict__ w0, const float* __restrict__ w1,
                            const float* __restrict__ w2, const float* __restrict__ w3,
                            const float* __restrict__ w4, const float* __restrict__ w5,
                            const float* __restrict__ w6, const float* __restrict__ w7,
                            unsigned short* __restrict__ dst) {
  const float* Ws[8] = {w0, w1, w2, w3, w4, w5, w6, w7};
  const float* src = Ws[blockIdx.y];
  int idx = blockIdx.x * 256 + threadIdx.x;         // 0..4095 float4s
  float4 v = *(const float4*)&src[(size_t)idx * 4];
  us4 p;
  p.x = f2bf(v.x); p.y = f2bf(v.y); p.z = f2bf(v.z); p.w = f2bf(v.w);
  *(us4*)&dst[(size_t)blockIdx.y * 16384 + (size_t)idx * 4] = p;
}

// ---------------------------------------------------------------------------
// epb[i][j] = bf16(exp(pos_bias[i][j])), i<256, j<1024; epbT = transpose.
// ---------------------------------------------------------------------------
__global__ void epb_kernel(const float* __restrict__ pb,
                           unsigned short* __restrict__ epb,
                           unsigned short* __restrict__ epbT) {
  __shared__ unsigned short t[32][33];
  const int j0 = (blockIdx.x & 31) * 32, i0 = (blockIdx.x >> 5) * 32;
  const int tx = threadIdx.x & 31, ty = threadIdx.x >> 5;
#pragma unroll
  for (int r = 0; r < 4; ++r) {
    int i = i0 + ty + r * 8;
    unsigned short u = f2bf(__expf(pb[(size_t)i * 1024 + j0 + tx]));
    epb[(size_t)i * 1024 + j0 + tx] = u;
    t[ty + r * 8][tx] = u;
  }
  __syncthreads();
#pragma unroll
  for (int r = 0; r < 4; ++r)
    epbT[(size_t)(j0 + ty + r * 8) * 256 + i0 + tx] = t[tx][ty + r * 8];
}

// ---------------------------------------------------------------------------
// Fused Q/K/V projection per side (bf16 weights):
//   sigQ[t,d]  = bf16(sigmoid(X@Wq^T + bq))
//   eKT[b,d,t] = bf16( mask[t] ? exp(X@Wk^T + bk) : 0 )   (transposed)
//   eKVT       = eK * (X@Wv^T + bv)                        (transposed)
// Block: 64 tokens x 128 d, 256 thr (4 waves, wave = 64t x 32d).
// ---------------------------------------------------------------------------
template <int T>
__global__ __launch_bounds__(256) void proj3(
    const float* __restrict__ X, const int* __restrict__ mask,
    const unsigned short* __restrict__ Wq, const float* __restrict__ bq,
    const unsigned short* __restrict__ Wk, const float* __restrict__ bk_,
    const unsigned short* __restrict__ Wv, const float* __restrict__ bv,
    unsigned short* __restrict__ sigQ, unsigned short* __restrict__ eKT,
    unsigned short* __restrict__ eKVT) {
  __shared__ unsigned short smem[2 * 128 * 72];  // xL aliases front
  unsigned short* xL = smem;                     // 64*136 us
  const int tid = threadIdx.x;
  const int g0 = blockIdx.x * 64;
  const int b = g0 / T;
  const int tl0 = g0 - b * T;

#pragma unroll
  for (int r = 0; r < 8; ++r) {
    int i4 = tid + 256 * r;                      // 2048 float4 = 64x128
    int t = i4 >> 5, k4 = (i4 & 31) * 4;
    float4 v = *(const float4*)&X[(size_t)(g0 + t) * 128 + k4];
    us4 p;
    p.x = f2bf(v.x); p.y = f2bf(v.y); p.z = f2bf(v.z); p.w = f2bf(v.w);
    *(us4*)&xL[t * 136 + k4] = p;
  }
  __syncthreads();

  const int lane = tid & 63, wave = tid >> 6;
  const int lo = lane & 15, hi = lane >> 4;
  const int d0 = wave * 32;

  f32x4 aQ[4][2], aK[4][2], aV[4][2];
#pragma unroll
  for (int a = 0; a < 4; ++a)
#pragma unroll
    for (int s = 0; s < 2; ++s)
#pragma unroll
      for (int r = 0; r < 4; ++r) { aQ[a][s][r] = 0.f; aK[a][s][r] = 0.f; aV[a][s][r] = 0.f; }

#pragma unroll
  for (int kt = 0; kt < 128; kt += 32) {
    bf16x8 bQ[2], bK[2], bV[2];
#pragma unroll
    for (int s = 0; s < 2; ++s) {
      size_t roff = (size_t)(d0 + s * 16 + lo) * 128 + kt + hi * 8;
      bQ[s] = *(const bf16x8*)&Wq[roff];
      bK[s] = *(const bf16x8*)&Wk[roff];
      bV[s] = *(const bf16x8*)&Wv[roff];
    }
#pragma unroll
    for (int a = 0; a < 4; ++a) {
      bf16x8 af = *(const bf16x8*)&xL[(a * 16 + lo) * 136 + kt + hi * 8];
#pragma unroll
      for (int s = 0; s < 2; ++s) {
        aQ[a][s] = __builtin_amdgcn_mfma_f32_16x16x32_bf16(af, bQ[s], aQ[a][s], 0, 0, 0);
        aK[a][s] = __builtin_amdgcn_mfma_f32_16x16x32_bf16(af, bK[s], aK[a][s], 0, 0, 0);
        aV[a][s] = __builtin_amdgcn_mfma_f32_16x16x32_bf16(af, bV[s], aV[a][s], 0, 0, 0);
      }
    }
  }

  // Q epilogue: sigmoid, bf16 store
#pragma unroll
  for (int s = 0; s < 2; ++s) {
    int d = d0 + s * 16 + lo;
    float bb = bq[d];
#pragma unroll
    for (int a = 0; a < 4; ++a)
#pragma unroll
      for (int r = 0; r < 4; ++r) {
        int t = g0 + a * 16 + hi * 4 + r;
        float q = aQ[a][s][r] + bb;
        sigQ[(size_t)t * 128 + d] = f2bf(1.f / (1.f + __expf(-q)));
      }
  }

  __syncthreads();  // xL reads done; reuse smem for transpose
  unsigned short* ekL = smem;           // [128][72]
  unsigned short* ekvL = smem + 9216;   // [128][72]
#pragma unroll
  for (int s = 0; s < 2; ++s) {
    int d = d0 + s * 16 + lo;
    float bbk = bk_[d], bbv = bv[d];
#pragma unroll
    for (int a = 0; a < 4; ++a)
#pragma unroll
      for (int r = 0; r < 4; ++r) {
        int tl = a * 16 + hi * 4 + r;    // 0..63
        int mk = mask[g0 + tl];
        float ek = mk ? __expf(aK[a][s][r] + bbk) : 0.f;
        float ekv = ek * (aV[a][s][r] + bbv);
        ekL[d * 72 + tl] = f2bf(ek);
        ekvL[d * 72 + tl] = f2bf(ekv);
      }
  }
  __syncthreads();
#pragma unroll
  for (int r = 0; r < 8; ++r) {
    int q = tid + 256 * r;               // 2048 chunks: 2 arrays x 128d x 8
    int arr = q >> 10, qq = q & 1023;
    int d = qq >> 3, c = qq & 7;
    us8 v = *(const us8*)&smem[arr * 9216 + d * 72 + c * 8];
    unsigned short* dst = arr ? eKVT : eKT;
    *(us8*)&dst[((size_t)b * 128 + d) * T + tl0 + c * 8] = v;
  }
}

// ---------------------------------------------------------------------------
// Unified AFT GEMM + fused final projection + masked row-max (encoded atomics).
// Block tile 128i x 128d (4 waves 2x2, wave 64i x 64d). K-step 64 j.
// Blocks [0,128): drug side (TJ=1024); [128,640): protein side (TJ=256).
// Epilogue: Y bf16 -> LDS [128][136], Z = Y @ Wp^T + bp (MFMA, K=128),
// masked max over i, order-preserving-encoded atomicMax into outEnc.
// ---------------------------------------------------------------------------
__global__ __launch_bounds__(256, 2) void aft_all(
    const unsigned short* __restrict__ epb, const unsigned short* __restrict__ epbT,
    const unsigned short* __restrict__ eKTd, const unsigned short* __restrict__ eKVTd,
    const unsigned short* __restrict__ eKTp, const unsigned short* __restrict__ eKVTp,
    const unsigned short* __restrict__ sigQd, const unsigned short* __restrict__ sigQp,
    const int* __restrict__ smask, const int* __restrict__ pmask,
    const unsigned short* __restrict__ Wpd, const float* __restrict__ bpd,
    const unsigned short* __restrict__ Wpp, const float* __restrict__ bpp,
    unsigned int* __restrict__ outEnc) {
  __shared__ unsigned short smem[17408];     // max(2*128*64, 128*136) us
  unsigned short* bkL = smem;                // [128][64] swizzled
  unsigned short* bvL = smem + 8192;

  const int blk = blockIdx.x;
  const unsigned short *Ap, *KT, *VT, *SQ, *Wp;
  const float* bp;
  const int* msk;
  unsigned int* oEnc;
  int b, i0, TJ, Ti, astr;
  if (blk < 128) {  // drug queries over protein keys
    b = blk >> 1; i0 = (blk & 1) * 128; TJ = 1024; Ti = 256;
    Ap = epb; astr = 1024; KT = eKTp; VT = eKVTp; SQ = sigQd;
    Wp = Wpd; bp = bpd; msk = smask + b * 256 + i0; oEnc = outEnc;
  } else {          // protein queries over drug keys
    int k = blk - 128;
    b = k >> 3; i0 = (k & 7) * 128; TJ = 256; Ti = 1024;
    Ap = epbT; astr = 256; KT = eKTd; VT = eKVTd; SQ = sigQp;
    Wp = Wpp; bp = bpp; msk = pmask + b * 1024 + i0; oEnc = outEnc + 8192;
  }

  const int tid = threadIdx.x, lane = tid & 63, w = tid >> 6;
  const int lo = lane & 15, hi = lane >> 4;
  const int wi = (w >> 1) * 64, wd = (w & 1) * 64;
  const unsigned short* KTb = KT + (size_t)b * 128 * TJ;
  const unsigned short* VTb = VT + (size_t)b * 128 * TJ;
  const int slotbase = w * 256;   // this wave's 256 of 1024 tile chunks

  f32x4 aN[4][4], aD[4][4];
#pragma unroll
  for (int a = 0; a < 4; ++a)
#pragma unroll
    for (int n = 0; n < 4; ++n)
#pragma unroll
      for (int r = 0; r < 4; ++r) { aN[a][n][r] = 0.f; aD[a][n][r] = 0.f; }

  for (int jt = 0; jt < TJ; jt += 64) {
    __syncthreads();   // previous tile's reads complete
#pragma unroll
    for (int it = 0; it < 4; ++it) {
      int slot = slotbase + it * 64 + lane;
      int r = slot >> 3, sc = slot & 7;
      int cg = sc ^ (r & 7);                       // XOR swizzle
      size_t goff = (size_t)r * TJ + jt + cg * 8;  // us offset
      gld16(KTb + goff, &bkL[(slotbase + it * 64) * 8]);
      gld16(VTb + goff, &bvL[(slotbase + it * 64) * 8]);
    }
    bf16x8 af[4][2];
#pragma unroll
    for (int a = 0; a < 4; ++a)
#pragma unroll
      for (int kt = 0; kt < 2; ++kt)
        af[a][kt] = *(const bf16x8*)
            &Ap[(size_t)(i0 + wi + a * 16 + lo) * astr + jt + kt * 32 + hi * 8];
    __syncthreads();   // drains vmcnt -> LDS tiles ready
#pragma unroll
    for (int kt = 0; kt < 2; ++kt) {
      bf16x8 bk[4], bv[4];
#pragma unroll
      for (int n = 0; n < 4; ++n) {
        int row = wd + n * 16 + lo;
        int sc = ((kt * 4 + hi) ^ (row & 7)) * 8;
        bk[n] = *(const bf16x8*)&bkL[row * 64 + sc];
        bv[n] = *(const bf16x8*)&bvL[row * 64 + sc];
      }
#pragma unroll
      for (int a = 0; a < 4; ++a)
#pragma unroll
        for (int n = 0; n < 4; ++n) {
          aN[a][n] = __builtin_amdgcn_mfma_f32_16x16x32_bf16(af[a][kt], bv[n], aN[a][n], 0, 0, 0);
          aD[a][n] = __builtin_amdgcn_mfma_f32_16x16x32_bf16(af[a][kt], bk[n], aD[a][n], 0, 0, 0);
        }
    }
  }

  // ---- epilogue: Y = sig(Q)*num/den -> LDS bf16 [128 i][136 stride]
  __syncthreads();
  unsigned short* yL = smem;
#pragma unroll
  for (int a = 0; a < 4; ++a)
#pragma unroll
    for (int n = 0; n < 4; ++n) {
      int iL = wi + a * 16 + hi * 4;
      int d = wd + n * 16 + lo;
#pragma unroll
      for (int r = 0; r < 4; ++r) {
        size_t off = ((size_t)b * Ti + i0 + iL + r) * 128 + d;
        float s = bf2f(SQ[off]);
        float y = s * __fdividef(aN[a][n][r], aD[a][n][r]);
        yL[(iL + r) * 136 + d] = f2bf(y);
      }
    }
  __syncthreads();

  // ---- Z = Y @ Wp^T (K=128), bias, masked row-max, encoded atomicMax
  f32x4 aZ[4][4];
#pragma unroll
  for (int a = 0; a < 4; ++a)
#pragma unroll
    for (int n = 0; n < 4; ++n)
#pragma unroll
      for (int r = 0; r < 4; ++r) aZ[a][n][r] = 0.f;

#pragma unroll
  for (int kt = 0; kt < 128; kt += 32) {
    bf16x8 bw[4];
#pragma unroll
    for (int n = 0; n < 4; ++n)
      bw[n] = *(const bf16x8*)&Wp[(size_t)(wd + n * 16 + lo) * 128 + kt + hi * 8];
#pragma unroll
    for (int a = 0; a < 4; ++a) {
      bf16x8 af = *(const bf16x8*)&yL[(wi + a * 16 + lo) * 136 + kt + hi * 8];
#pragma unroll
      for (int n = 0; n < 4; ++n)
        aZ[a][n] = __builtin_amdgcn_mfma_f32_16x16x32_bf16(af, bw[n], aZ[a][n], 0, 0, 0);
    }
  }

#pragma unroll
  for (int n = 0; n < 4; ++n) {
    int d = wd + n * 16 + lo;
    float bb = bp[d];
    float m = NEGV;
#pragma unroll
    for (int a = 0; a < 4; ++a)
#pragma unroll
      for (int r = 0; r < 4; ++r) {
        int iL = wi + a * 16 + hi * 4 + r;
        float z = aZ[a][n][r] + bb;
        m = msk[iL] ? fmaxf(m, z) : m;
      }
    m = fmaxf(m, __shfl_xor(m, 16, 64));
    m = fmaxf(m, __shfl_xor(m, 32, 64));
    if (hi == 0) {
      unsigned bits = __float_as_uint(m);
      unsigned key = (bits & 0x80000000u) ? ~bits : (bits | 0x80000000u);
      atomicMax(&oEnc[b * 128 + d], key);
    }
  }
}

// ---------------------------------------------------------------------------
__global__ void out_init(unsigned int* o) {
  o[blockIdx.x * 256 + threadIdx.x] = 0u;
}
__global__ void out_decode(unsigned int* o) {
  int i = blockIdx.x * 256 + threadIdx.x;
  unsigned k = o[i];
  unsigned bits = (k & 0x80000000u) ? (k ^ 0x80000000u) : ~k;
  ((float*)o)[i] = __uint_as_float(bits);
}

// ---------------------------------------------------------------------------
extern "C" void kernel_launch(void* const* d_in, const int* in_sizes, int n_in,
                              void* d_out, int out_size, void* d_ws, size_t ws_size,
                              hipStream_t stream) {
  const float* smiles = (const float*)d_in[0];
  const float* prot   = (const float*)d_in[1];
  const int* smask = (const int*)d_in[2];
  const int* pmask = (const int*)d_in[3];
  const float* pos_bias = (const float*)d_in[4];
  const float* Wqd = (const float*)d_in[5];  const float* bqd = (const float*)d_in[6];
  const float* Wkp = (const float*)d_in[7];  const float* bkp = (const float*)d_in[8];
  const float* Wvp = (const float*)d_in[9];  const float* bvp = (const float*)d_in[10];
  const float* Wqp = (const float*)d_in[11]; const float* bqp = (const float*)d_in[12];
  const float* Wkd = (const float*)d_in[13]; const float* bkd = (const float*)d_in[14];
  const float* Wvd = (const float*)d_in[15]; const float* bvd = (const float*)d_in[16];
  const float* Wpd = (const float*)d_in[17]; const float* bpd = (const float*)d_in[18];
  const float* Wpp = (const float*)d_in[19]; const float* bpp = (const float*)d_in[20];

  // Workspace (unsigned short units)
  unsigned short* u = (unsigned short*)d_ws;
  unsigned short* eKTp  = u;                 // 8,388,608
  unsigned short* eKVTp = eKTp + 8388608;    // 8,388,608
  unsigned short* eKTd  = eKVTp + 8388608;   // 2,097,152
  unsigned short* eKVTd = eKTd + 2097152;    // 2,097,152
  unsigned short* sigQd = eKVTd + 2097152;   // 2,097,152
  unsigned short* sigQp = sigQd + 2097152;   // 8,388,608
  unsigned short* epb_  = sigQp + 8388608;   // 262,144
  unsigned short* epbT_ = epb_ + 262144;     // 262,144
  unsigned short* Wbf   = epbT_ + 262144;    // 8 * 16,384
  // Wbf order: [Wqd, Wkd, Wvd, Wqp, Wkp, Wvp, Wpd, Wpp]

  dim3 blk(256);

  out_init<<<64, blk, 0, stream>>>((unsigned int*)d_out);
  wcvt_kernel<<<dim3(16, 8), blk, 0, stream>>>(Wqd, Wkd, Wvd, Wqp, Wkp, Wvp, Wpd, Wpp, Wbf);
  epb_kernel<<<256, blk, 0, stream>>>(pos_bias, epb_, epbT_);

  proj3<256><<<256, blk, 0, stream>>>(smiles, smask,
      Wbf + 0 * 16384, bqd, Wbf + 1 * 16384, bkd, Wbf + 2 * 16384, bvd,
      sigQd, eKTd, eKVTd);
  proj3<1024><<<1024, blk, 0, stream>>>(prot, pmask,
      Wbf + 3 * 16384, bqp, Wbf + 4 * 16384, bkp, Wbf + 5 * 16384, bvp,
      sigQp, eKTp, eKVTp);

  aft_all<<<640, blk, 0, stream>>>(epb_, epbT_, eKTd, eKVTd, eKTp, eKVTp,
                                   sigQd, sigQp, smask, pmask,
                                   Wbf + 6 * 16384, bpd, Wbf + 7 * 16384, bpp,
                                   (unsigned int*)d_out);

  out_decode<<<64, blk, 0, stream>>>((unsigned int*)d_out);
}

// Round 5
// 196.478 us; speedup vs baseline: 4.5103x; 1.0545x over previous
//
#include <hip/hip_runtime.h>
#include <cstdint>
#include <cstddef>

#define NEGV -1e9f

typedef __bf16 bf16x8 __attribute__((ext_vector_type(8)));
typedef float f32x4 __attribute__((ext_vector_type(4)));
typedef unsigned short us4 __attribute__((ext_vector_type(4)));
typedef unsigned short us8 __attribute__((ext_vector_type(8)));

__device__ __forceinline__ unsigned short f2bf(float f) {
  unsigned int u = __float_as_uint(f);
  u += 0x7fffu + ((u >> 16) & 1u);   // round-to-nearest-even
  return (unsigned short)(u >> 16);
}
__device__ __forceinline__ float bf2f(unsigned short u) {
  return __uint_as_float(((unsigned)u) << 16);
}

// async 16B global -> LDS (dest = wave-uniform base + lane*16)
__device__ __forceinline__ void gld16(const void* g, void* l) {
  __builtin_amdgcn_global_load_lds(
      (const __attribute__((address_space(1))) unsigned int*)g,
      (__attribute__((address_space(3))) unsigned int*)l, 16, 0, 0);
}

// ---------------------------------------------------------------------------
// prep: out_init (blocks 0..63) + wcvt 8 weight mats (64..191) + epb (192..447)
// ---------------------------------------------------------------------------
__global__ void prep_kernel(const float* __restrict__ w0, const float* __restrict__ w1,
                            const float* __restrict__ w2, const float* __restrict__ w3,
                            const float* __restrict__ w4, const float* __restrict__ w5,
                            const float* __restrict__ w6, const float* __restrict__ w7,
                            unsigned short* __restrict__ Wbf,
                            const float* __restrict__ pb,
                            unsigned short* __restrict__ epb,
                            unsigned short* __restrict__ epbT,
                            unsigned int* __restrict__ outEnc) {
  __shared__ unsigned short t[32][33];
  const int blk = blockIdx.x, tid = threadIdx.x;
  if (blk < 64) {
    outEnc[blk * 256 + tid] = 0u;
    return;
  }
  if (blk < 192) {
    const float* Ws[8] = {w0, w1, w2, w3, w4, w5, w6, w7};
    int idx = (blk - 64) * 256 + tid;        // 0..32767 float4s
    int mat = idx >> 12, off = idx & 4095;
    float4 v = *(const float4*)&Ws[mat][(size_t)off * 4];
    us4 p;
    p.x = f2bf(v.x); p.y = f2bf(v.y); p.z = f2bf(v.z); p.w = f2bf(v.w);
    *(us4*)&Wbf[(size_t)mat * 16384 + (size_t)off * 4] = p;
    return;
  }
  const int bid = blk - 192;
  const int j0 = (bid & 31) * 32, i0 = (bid >> 5) * 32;
  const int tx = tid & 31, ty = tid >> 5;
#pragma unroll
  for (int r = 0; r < 4; ++r) {
    int i = i0 + ty + r * 8;
    unsigned short u = f2bf(__expf(pb[(size_t)i * 1024 + j0 + tx]));
    epb[(size_t)i * 1024 + j0 + tx] = u;
    t[ty + r * 8][tx] = u;
  }
  __syncthreads();
#pragma unroll
  for (int r = 0; r < 4; ++r)
    epbT[(size_t)(j0 + ty + r * 8) * 256 + i0 + tx] = t[tx][ty + r * 8];
}

// ---------------------------------------------------------------------------
// Fused Q/K/V projections, BOTH sides in one launch.
// Blocks [0,256): drug (T=256); [256,1280): protein (T=1024).
//   sigQ[t,d]  = bf16(sigmoid(X@Wq^T + bq))
//   eKT[b,d,t] = bf16( mask[t] ? exp(X@Wk^T + bk) : 0 )   (transposed)
//   eKVT       = eK * (X@Wv^T + bv)                        (transposed)
// ---------------------------------------------------------------------------
__global__ __launch_bounds__(256) void proj3_all(
    const float* __restrict__ smiles, const float* __restrict__ prot,
    const int* __restrict__ smask, const int* __restrict__ pmask,
    const unsigned short* __restrict__ Wbf,
    const float* __restrict__ bqd, const float* __restrict__ bkd, const float* __restrict__ bvd,
    const float* __restrict__ bqp, const float* __restrict__ bkp, const float* __restrict__ bvp,
    unsigned short* __restrict__ sigQd, unsigned short* __restrict__ eKTd,
    unsigned short* __restrict__ eKVTd,
    unsigned short* __restrict__ sigQp, unsigned short* __restrict__ eKTp,
    unsigned short* __restrict__ eKVTp) {
  __shared__ unsigned short smem[2 * 128 * 72];
  unsigned short* xL = smem;                     // 64*136 us
  const int tid = threadIdx.x;

  const float* X; const int* mask;
  const unsigned short *Wq, *Wk, *Wv;
  const float *bq, *bk_, *bv;
  unsigned short *sigQ, *eKT, *eKVT;
  int T, g0;
  if (blockIdx.x < 256) {
    X = smiles; mask = smask; T = 256; g0 = blockIdx.x * 64;
    Wq = Wbf; Wk = Wbf + 16384; Wv = Wbf + 32768;
    bq = bqd; bk_ = bkd; bv = bvd;
    sigQ = sigQd; eKT = eKTd; eKVT = eKVTd;
  } else {
    X = prot; mask = pmask; T = 1024; g0 = (blockIdx.x - 256) * 64;
    Wq = Wbf + 3 * 16384; Wk = Wbf + 4 * 16384; Wv = Wbf + 5 * 16384;
    bq = bqp; bk_ = bkp; bv = bvp;
    sigQ = sigQp; eKT = eKTp; eKVT = eKVTp;
  }
  const int b = g0 / T;
  const int tl0 = g0 - b * T;

#pragma unroll
  for (int r = 0; r < 8; ++r) {
    int i4 = tid + 256 * r;                      // 2048 float4 = 64x128
    int t = i4 >> 5, k4 = (i4 & 31) * 4;
    float4 v = *(const float4*)&X[(size_t)(g0 + t) * 128 + k4];
    us4 p;
    p.x = f2bf(v.x); p.y = f2bf(v.y); p.z = f2bf(v.z); p.w = f2bf(v.w);
    *(us4*)&xL[t * 136 + k4] = p;
  }
  __syncthreads();

  const int lane = tid & 63, wave = tid >> 6;
  const int lo = lane & 15, hi = lane >> 4;
  const int d0 = wave * 32;

  f32x4 aQ[4][2], aK[4][2], aV[4][2];
#pragma unroll
  for (int a = 0; a < 4; ++a)
#pragma unroll
    for (int s = 0; s < 2; ++s)
#pragma unroll
      for (int r = 0; r < 4; ++r) { aQ[a][s][r] = 0.f; aK[a][s][r] = 0.f; aV[a][s][r] = 0.f; }

#pragma unroll
  for (int kt = 0; kt < 128; kt += 32) {
    bf16x8 bQ[2], bK[2], bV[2];
#pragma unroll
    for (int s = 0; s < 2; ++s) {
      size_t roff = (size_t)(d0 + s * 16 + lo) * 128 + kt + hi * 8;
      bQ[s] = *(const bf16x8*)&Wq[roff];
      bK[s] = *(const bf16x8*)&Wk[roff];
      bV[s] = *(const bf16x8*)&Wv[roff];
    }
#pragma unroll
    for (int a = 0; a < 4; ++a) {
      bf16x8 af = *(const bf16x8*)&xL[(a * 16 + lo) * 136 + kt + hi * 8];
#pragma unroll
      for (int s = 0; s < 2; ++s) {
        aQ[a][s] = __builtin_amdgcn_mfma_f32_16x16x32_bf16(af, bQ[s], aQ[a][s], 0, 0, 0);
        aK[a][s] = __builtin_amdgcn_mfma_f32_16x16x32_bf16(af, bK[s], aK[a][s], 0, 0, 0);
        aV[a][s] = __builtin_amdgcn_mfma_f32_16x16x32_bf16(af, bV[s], aV[a][s], 0, 0, 0);
      }
    }
  }

  // Q epilogue: sigmoid, bf16 store
#pragma unroll
  for (int s = 0; s < 2; ++s) {
    int d = d0 + s * 16 + lo;
    float bb = bq[d];
#pragma unroll
    for (int a = 0; a < 4; ++a)
#pragma unroll
      for (int r = 0; r < 4; ++r) {
        int t = g0 + a * 16 + hi * 4 + r;
        float q = aQ[a][s][r] + bb;
        sigQ[(size_t)t * 128 + d] = f2bf(1.f / (1.f + __expf(-q)));
      }
  }

  __syncthreads();  // xL reads done; reuse smem for transpose
  unsigned short* ekL = smem;           // [128][72]
  unsigned short* ekvL = smem + 9216;   // [128][72]
#pragma unroll
  for (int s = 0; s < 2; ++s) {
    int d = d0 + s * 16 + lo;
    float bbk = bk_[d], bbv = bv[d];
#pragma unroll
    for (int a = 0; a < 4; ++a)
#pragma unroll
      for (int r = 0; r < 4; ++r) {
        int tl = a * 16 + hi * 4 + r;    // 0..63
        int mk = mask[g0 + tl];
        float ek = mk ? __expf(aK[a][s][r] + bbk) : 0.f;
        float ekv = ek * (aV[a][s][r] + bbv);
        ekL[d * 72 + tl] = f2bf(ek);
        ekvL[d * 72 + tl] = f2bf(ekv);
      }
  }
  __syncthreads();
#pragma unroll
  for (int r = 0; r < 8; ++r) {
    int q = tid + 256 * r;               // 2048 chunks: 2 arrays x 128d x 8
    int arr = q >> 10, qq = q & 1023;
    int d = qq >> 3, c = qq & 7;
    us8 v = *(const us8*)&smem[arr * 9216 + d * 72 + c * 8];
    unsigned short* dst = arr ? eKVT : eKT;
    *(us8*)&dst[((size_t)b * 128 + d) * T + tl0 + c * 8] = v;
  }
}

// ---------------------------------------------------------------------------
// Unified AFT GEMM + fused final projection + masked row-max.
// Software-pipelined: double-buffered B tiles (gld16), prefetched A frags,
// non-draining barriers (s_waitcnt vmcnt(16) / lgkmcnt(0) + raw s_barrier).
// Block tile 128i x 128d (4 waves 2x2, wave 64i x 64d). K-step 64 j.
// XCD grouping: blk%8 == b%8 so same-b blocks share an XCD's L2.
// ---------------------------------------------------------------------------
__global__ __launch_bounds__(256, 2) void aft_all(
    const unsigned short* __restrict__ epb, const unsigned short* __restrict__ epbT,
    const unsigned short* __restrict__ eKTd, const unsigned short* __restrict__ eKVTd,
    const unsigned short* __restrict__ eKTp, const unsigned short* __restrict__ eKVTp,
    const unsigned short* __restrict__ sigQd, const unsigned short* __restrict__ sigQp,
    const int* __restrict__ smask, const int* __restrict__ pmask,
    const unsigned short* __restrict__ Wbf,
    const float* __restrict__ bpd, const float* __restrict__ bpp,
    unsigned int* __restrict__ outEnc) {
  __shared__ unsigned short smem[32768];     // dbuf: 2 x (bk 8192 + bv 8192) us

  const int blk = blockIdx.x;
  const unsigned short *Ap, *KT, *VT, *SQ, *Wp;
  const float* bp;
  const int* msk;
  unsigned int* oEnc;
  int b, i0, TJ, Ti, astr;
  if (blk < 128) {  // drug queries over protein keys; blk = itile*64 + b
    b = blk & 63; i0 = (blk >> 6) * 128; TJ = 1024; Ti = 256;
    Ap = epb; astr = 1024; KT = eKTp; VT = eKVTp; SQ = sigQd;
    Wp = Wbf + 6 * 16384; bp = bpd; msk = smask + b * 256 + i0; oEnc = outEnc;
  } else {          // protein queries over drug keys; k = itile*64 + b
    int k = blk - 128;
    b = k & 63; i0 = (k >> 6) * 128; TJ = 256; Ti = 1024;
    Ap = epbT; astr = 256; KT = eKTd; VT = eKVTd; SQ = sigQp;
    Wp = Wbf + 7 * 16384; bp = bpp; msk = pmask + b * 1024 + i0; oEnc = outEnc + 8192;
  }

  const int tid = threadIdx.x, lane = tid & 63, w = tid >> 6;
  const int lo = lane & 15, hi = lane >> 4;
  const int wi = (w >> 1) * 64, wd = (w & 1) * 64;
  const unsigned short* KTb = KT + (size_t)b * 128 * TJ;
  const unsigned short* VTb = VT + (size_t)b * 128 * TJ;
  const int slotbase = w * 256;   // this wave's 256 of 1024 tile chunks

  // stage B tile (64 j at jt) into buffer p: 8 gld16 per wave
  auto stage = [&](int jt, int p) {
    unsigned short* bkL = smem + p * 16384;
    unsigned short* bvL = bkL + 8192;
#pragma unroll
    for (int it = 0; it < 4; ++it) {
      int slot = slotbase + it * 64 + lane;
      int r = slot >> 3, sc = slot & 7;
      int cg = sc ^ (r & 7);                       // XOR swizzle
      size_t goff = (size_t)r * TJ + jt + cg * 8;  // us offset
      gld16(KTb + goff, &bkL[(slotbase + it * 64) * 8]);
      gld16(VTb + goff, &bvL[(slotbase + it * 64) * 8]);
    }
  };

  f32x4 aN[4][4], aD[4][4];
#pragma unroll
  for (int a = 0; a < 4; ++a)
#pragma unroll
    for (int n = 0; n < 4; ++n)
#pragma unroll
      for (int r = 0; r < 4; ++r) { aN[a][n][r] = 0.f; aD[a][n][r] = 0.f; }

  // prologue: tile 0 -> buf0, A frags for tile 0
  stage(0, 0);
  bf16x8 af_cur[4][2];
#pragma unroll
  for (int a = 0; a < 4; ++a)
#pragma unroll
    for (int kt = 0; kt < 2; ++kt)
      af_cur[a][kt] = *(const bf16x8*)
          &Ap[(size_t)(i0 + wi + a * 16 + lo) * astr + kt * 32 + hi * 8];

  int p = 0;
  for (int jt = 0; jt < TJ; jt += 64) {
    const int jn = (jt + 64 < TJ) ? jt + 64 : jt;   // clamped prefetch
    stage(jn, p ^ 1);                                // 8 gld16
    bf16x8 af_nxt[4][2];
#pragma unroll
    for (int a = 0; a < 4; ++a)
#pragma unroll
      for (int kt = 0; kt < 2; ++kt)
        af_nxt[a][kt] = *(const bf16x8*)
            &Ap[(size_t)(i0 + wi + a * 16 + lo) * astr + jn + kt * 32 + hi * 8];
    // wait: everything older than this iter's 16 vmem issues (i.e. tile jt's
    // gld16 + af_cur loads) has retired; then barrier WITHOUT vmcnt drain.
    asm volatile("s_waitcnt vmcnt(16)\ns_barrier" ::: "memory");

    const unsigned short* bkL = smem + p * 16384;
    const unsigned short* bvL = bkL + 8192;
#pragma unroll
    for (int kt = 0; kt < 2; ++kt) {
      bf16x8 bk[4], bv[4];
#pragma unroll
      for (int n = 0; n < 4; ++n) {
        int row = wd + n * 16 + lo;
        int sc = ((kt * 4 + hi) ^ (row & 7)) * 8;
        bk[n] = *(const bf16x8*)&bkL[row * 64 + sc];
        bv[n] = *(const bf16x8*)&bvL[row * 64 + sc];
      }
#pragma unroll
      for (int a = 0; a < 4; ++a)
#pragma unroll
        for (int n = 0; n < 4; ++n) {
          aN[a][n] = __builtin_amdgcn_mfma_f32_16x16x32_bf16(af_cur[a][kt], bv[n], aN[a][n], 0, 0, 0);
          aD[a][n] = __builtin_amdgcn_mfma_f32_16x16x32_bf16(af_cur[a][kt], bk[n], aD[a][n], 0, 0, 0);
        }
    }
    // readers of buf p done (own lgkm drained; barrier syncs waves) before
    // next iteration overwrites buf p.
    asm volatile("s_waitcnt lgkmcnt(0)\ns_barrier" ::: "memory");
#pragma unroll
    for (int a = 0; a < 4; ++a)
#pragma unroll
      for (int kt = 0; kt < 2; ++kt)
        af_cur[a][kt] = af_nxt[a][kt];
    p ^= 1;
  }

  // ---- epilogue: Y = sig(Q)*num/den -> LDS bf16 [128 i][136 stride]
  __syncthreads();   // full drain: in-flight clamped gld16 must land before reuse
  unsigned short* yL = smem;
#pragma unroll
  for (int a = 0; a < 4; ++a)
#pragma unroll
    for (int n = 0; n < 4; ++n) {
      int iL = wi + a * 16 + hi * 4;
      int d = wd + n * 16 + lo;
#pragma unroll
      for (int r = 0; r < 4; ++r) {
        size_t off = ((size_t)b * Ti + i0 + iL + r) * 128 + d;
        float s = bf2f(SQ[off]);
        float y = s * __fdividef(aN[a][n][r], aD[a][n][r]);
        yL[(iL + r) * 136 + d] = f2bf(y);
      }
    }
  __syncthreads();

  // ---- Z = Y @ Wp^T (K=128), bias, masked row-max, encoded atomicMax
  f32x4 aZ[4][4];
#pragma unroll
  for (int a = 0; a < 4; ++a)
#pragma unroll
    for (int n = 0; n < 4; ++n)
#pragma unroll
      for (int r = 0; r < 4; ++r) aZ[a][n][r] = 0.f;

#pragma unroll
  for (int kt = 0; kt < 128; kt += 32) {
    bf16x8 bw[4];
#pragma unroll
    for (int n = 0; n < 4; ++n)
      bw[n] = *(const bf16x8*)&Wp[(size_t)(wd + n * 16 + lo) * 128 + kt + hi * 8];
#pragma unroll
    for (int a = 0; a < 4; ++a) {
      bf16x8 af = *(const bf16x8*)&yL[(wi + a * 16 + lo) * 136 + kt + hi * 8];
#pragma unroll
      for (int n = 0; n < 4; ++n)
        aZ[a][n] = __builtin_amdgcn_mfma_f32_16x16x32_bf16(af, bw[n], aZ[a][n], 0, 0, 0);
    }
  }

#pragma unroll
  for (int n = 0; n < 4; ++n) {
    int d = wd + n * 16 + lo;
    float bb = bp[d];
    float m = NEGV;
#pragma unroll
    for (int a = 0; a < 4; ++a)
#pragma unroll
      for (int r = 0; r < 4; ++r) {
        int iL = wi + a * 16 + hi * 4 + r;
        float z = aZ[a][n][r] + bb;
        m = msk[iL] ? fmaxf(m, z) : m;
      }
    m = fmaxf(m, __shfl_xor(m, 16, 64));
    m = fmaxf(m, __shfl_xor(m, 32, 64));
    if (hi == 0) {
      unsigned bits = __float_as_uint(m);
      unsigned key = (bits & 0x80000000u) ? ~bits : (bits | 0x80000000u);
      atomicMax(&oEnc[b * 128 + d], key);
    }
  }
}

// ---------------------------------------------------------------------------
__global__ void out_decode(unsigned int* o) {
  int i = blockIdx.x * 256 + threadIdx.x;
  unsigned k = o[i];
  unsigned bits = (k & 0x80000000u) ? (k ^ 0x80000000u) : ~k;
  ((float*)o)[i] = __uint_as_float(bits);
}

// ---------------------------------------------------------------------------
extern "C" void kernel_launch(void* const* d_in, const int* in_sizes, int n_in,
                              void* d_out, int out_size, void* d_ws, size_t ws_size,
                              hipStream_t stream) {
  const float* smiles = (const float*)d_in[0];
  const float* prot   = (const float*)d_in[1];
  const int* smask = (const int*)d_in[2];
  const int* pmask = (const int*)d_in[3];
  const float* pos_bias = (const float*)d_in[4];
  const float* Wqd = (const float*)d_in[5];  const float* bqd = (const float*)d_in[6];
  const float* Wkp = (const float*)d_in[7];  const float* bkp = (const float*)d_in[8];
  const float* Wvp = (const float*)d_in[9];  const float* bvp = (const float*)d_in[10];
  const float* Wqp = (const float*)d_in[11]; const float* bqp = (const float*)d_in[12];
  const float* Wkd = (const float*)d_in[13]; const float* bkd = (const float*)d_in[14];
  const float* Wvd = (const float*)d_in[15]; const float* bvd = (const float*)d_in[16];
  const float* Wpd = (const float*)d_in[17]; const float* bpd = (const float*)d_in[18];
  const float* Wpp = (const float*)d_in[19]; const float* bpp = (const float*)d_in[20];

  // Workspace (unsigned short units)
  unsigned short* u = (unsigned short*)d_ws;
  unsigned short* eKTp  = u;                 // 8,388,608
  unsigned short* eKVTp = eKTp + 8388608;    // 8,388,608
  unsigned short* eKTd  = eKVTp + 8388608;   // 2,097,152
  unsigned short* eKVTd = eKTd + 2097152;    // 2,097,152
  unsigned short* sigQd = eKVTd + 2097152;   // 2,097,152
  unsigned short* sigQp = sigQd + 2097152;   // 8,388,608
  unsigned short* epb_  = sigQp + 8388608;   // 262,144
  unsigned short* epbT_ = epb_ + 262144;     // 262,144
  unsigned short* Wbf   = epbT_ + 262144;    // 8 * 16,384
  // Wbf order: [Wqd, Wkd, Wvd, Wqp, Wkp, Wvp, Wpd, Wpp]

  dim3 blk(256);

  prep_kernel<<<448, blk, 0, stream>>>(Wqd, Wkd, Wvd, Wqp, Wkp, Wvp, Wpd, Wpp,
                                       Wbf, pos_bias, epb_, epbT_,
                                       (unsigned int*)d_out);

  proj3_all<<<1280, blk, 0, stream>>>(smiles, prot, smask, pmask, Wbf,
                                      bqd, bkd, bvd, bqp, bkp, bvp,
                                      sigQd, eKTd, eKVTd, sigQp, eKTp, eKVTp);

  aft_all<<<640, blk, 0, stream>>>(epb_, epbT_, eKTd, eKVTd, eKTp, eKVTp,
                                   sigQd, sigQp, smask, pmask, Wbf,
                                   bpd, bpp, (unsigned int*)d_out);

  out_decode<<<64, blk, 0, stream>>>((unsigned int*)d_out);
}

// Round 6
// 181.596 us; speedup vs baseline: 4.8800x; 1.0820x over previous
//
#include <hip/hip_runtime.h>
#include <cstdint>
#include <cstddef>

#define NEGV -1e9f

typedef __bf16 bf16x8 __attribute__((ext_vector_type(8)));
typedef float f32x4 __attribute__((ext_vector_type(4)));
typedef unsigned short us4 __attribute__((ext_vector_type(4)));
typedef unsigned short us8 __attribute__((ext_vector_type(8)));

__device__ __forceinline__ unsigned short f2bf(float f) {
  unsigned int u = __float_as_uint(f);
  u += 0x7fffu + ((u >> 16) & 1u);   // round-to-nearest-even
  return (unsigned short)(u >> 16);
}
__device__ __forceinline__ float bf2f(unsigned short u) {
  return __uint_as_float(((unsigned)u) << 16);
}

// ===========================================================================
// Fragment-order layouts (16x16x32 MFMA, lane = hi*16+lo, hi=lane>>4, lo=lane&15):
//  A-frag table  AF[it][kt][lane][c]  : value(i = it*16+lo, j = kt*32+hi*8+c)
//  B-frag table  BF[b][kt][dt][lane][c]: value(d = dt*16+lo, j = kt*32+hi*8+c)
//  C-frag table  CF[b][it][dt][lane][r]: value(i = it*16+hi*4+r, d = dt*16+lo)
// All aft_all loads become 16B(us8)/8B(us4) per-lane coalesced; no LDS needed.
// ===========================================================================

// ---------------------------------------------------------------------------
// prep: out_init (0..63) + wcvt 8 weights (64..191) + plain epb/epbT (192..447)
// ---------------------------------------------------------------------------
__global__ void prep_kernel(const float* __restrict__ w0, const float* __restrict__ w1,
                            const float* __restrict__ w2, const float* __restrict__ w3,
                            const float* __restrict__ w4, const float* __restrict__ w5,
                            const float* __restrict__ w6, const float* __restrict__ w7,
                            unsigned short* __restrict__ Wbf,
                            const float* __restrict__ pb,
                            unsigned short* __restrict__ epb,
                            unsigned short* __restrict__ epbT,
                            unsigned int* __restrict__ outEnc) {
  __shared__ unsigned short t[32][33];
  const int blk = blockIdx.x, tid = threadIdx.x;
  if (blk < 64) {
    outEnc[blk * 256 + tid] = 0u;
    return;
  }
  if (blk < 192) {
    const float* Ws[8] = {w0, w1, w2, w3, w4, w5, w6, w7};
    int idx = (blk - 64) * 256 + tid;        // 0..32767 float4s
    int mat = idx >> 12, off = idx & 4095;
    float4 v = *(const float4*)&Ws[mat][(size_t)off * 4];
    us4 p;
    p.x = f2bf(v.x); p.y = f2bf(v.y); p.z = f2bf(v.z); p.w = f2bf(v.w);
    *(us4*)&Wbf[(size_t)mat * 16384 + (size_t)off * 4] = p;
    return;
  }
  const int bid = blk - 192;
  const int j0 = (bid & 31) * 32, i0 = (bid >> 5) * 32;
  const int tx = tid & 31, ty = tid >> 5;
#pragma unroll
  for (int r = 0; r < 4; ++r) {
    int i = i0 + ty + r * 8;
    unsigned short u = f2bf(__expf(pb[(size_t)i * 1024 + j0 + tx]));
    epb[(size_t)i * 1024 + j0 + tx] = u;
    t[ty + r * 8][tx] = u;
  }
  __syncthreads();
#pragma unroll
  for (int r = 0; r < 4; ++r)
    epbT[(size_t)(j0 + ty + r * 8) * 256 + i0 + tx] = t[tx][ty + r * 8];
}

// ---------------------------------------------------------------------------
// proj3_all: blocks [0,256) drug, [256,1280) protein projections;
//            blocks [1280,1536) pack epb/epbT into A-frag tables.
// Projections write sigQ in C-frag order, eK/eKV in B-frag order, directly
// from MFMA accumulators (registers are already fragment-shaped).
// ---------------------------------------------------------------------------
__global__ __launch_bounds__(256) void proj3_all(
    const float* __restrict__ smiles, const float* __restrict__ prot,
    const int* __restrict__ smask, const int* __restrict__ pmask,
    const unsigned short* __restrict__ Wbf,
    const float* __restrict__ bqd, const float* __restrict__ bkd, const float* __restrict__ bvd,
    const float* __restrict__ bqp, const float* __restrict__ bkp, const float* __restrict__ bvp,
    const unsigned short* __restrict__ epb, const unsigned short* __restrict__ epbT,
    unsigned short* __restrict__ AFd, unsigned short* __restrict__ AFp,
    unsigned short* __restrict__ SQd, unsigned short* __restrict__ BKd,
    unsigned short* __restrict__ BVd,
    unsigned short* __restrict__ SQp, unsigned short* __restrict__ BKp,
    unsigned short* __restrict__ BVp) {
  const int tid = threadIdx.x;

  if (blockIdx.x >= 1280) {   // ---- A-frag packing ----
    int sid = (blockIdx.x - 1280) * 256 + tid;   // 0..65535 us8-slots
    if (sid < 32768) {        // drug-query A: [it<16][kt<32][lane][8]
      int lane = sid & 63, kt = (sid >> 6) & 31, it = sid >> 11;
      int i = it * 16 + (lane & 15), j = kt * 32 + (lane >> 4) * 8;
      *(us8*)&AFd[(size_t)sid * 8] = *(const us8*)&epb[(size_t)i * 1024 + j];
    } else {                  // protein-query A: [it<64][kt<8][lane][8]
      int s2 = sid - 32768;
      int lane = s2 & 63, kt = (s2 >> 6) & 7, it = s2 >> 9;
      int i = it * 16 + (lane & 15), j = kt * 32 + (lane >> 4) * 8;
      *(us8*)&AFp[(size_t)s2 * 8] = *(const us8*)&epbT[(size_t)i * 256 + j];
    }
    return;
  }

  __shared__ unsigned short xL[64 * 136];   // 17408 B

  const float* X; const int* mask;
  const unsigned short *Wq, *Wk, *Wv;
  const float *bq, *bk_, *bv;
  unsigned short *SQ, *BK, *BV;
  int T, g0;
  if (blockIdx.x < 256) {
    X = smiles; mask = smask; T = 256; g0 = blockIdx.x * 64;
    Wq = Wbf; Wk = Wbf + 16384; Wv = Wbf + 32768;
    bq = bqd; bk_ = bkd; bv = bvd;
    SQ = SQd; BK = BKd; BV = BVd;
  } else {
    X = prot; mask = pmask; T = 1024; g0 = (blockIdx.x - 256) * 64;
    Wq = Wbf + 3 * 16384; Wk = Wbf + 4 * 16384; Wv = Wbf + 5 * 16384;
    bq = bqp; bk_ = bkp; bv = bvp;
    SQ = SQp; BK = BKp; BV = BVp;
  }
  const int b = g0 / T;
  const int tl0 = g0 - b * T;
  const int NIT = T / 16, NKT = T / 32;

#pragma unroll
  for (int r = 0; r < 8; ++r) {
    int i4 = tid + 256 * r;                      // 2048 float4 = 64x128
    int t = i4 >> 5, k4 = (i4 & 31) * 4;
    float4 v = *(const float4*)&X[(size_t)(g0 + t) * 128 + k4];
    us4 p;
    p.x = f2bf(v.x); p.y = f2bf(v.y); p.z = f2bf(v.z); p.w = f2bf(v.w);
    *(us4*)&xL[t * 136 + k4] = p;
  }
  __syncthreads();

  const int lane = tid & 63, wave = tid >> 6;
  const int lo = lane & 15, hi = lane >> 4;
  const int d0 = wave * 32;

  f32x4 aQ[4][2], aK[4][2], aV[4][2];
#pragma unroll
  for (int a = 0; a < 4; ++a)
#pragma unroll
    for (int s = 0; s < 2; ++s)
#pragma unroll
      for (int r = 0; r < 4; ++r) { aQ[a][s][r] = 0.f; aK[a][s][r] = 0.f; aV[a][s][r] = 0.f; }

#pragma unroll
  for (int kt = 0; kt < 128; kt += 32) {
    bf16x8 bQ[2], bK[2], bV[2];
#pragma unroll
    for (int s = 0; s < 2; ++s) {
      size_t roff = (size_t)(d0 + s * 16 + lo) * 128 + kt + hi * 8;
      bQ[s] = *(const bf16x8*)&Wq[roff];
      bK[s] = *(const bf16x8*)&Wk[roff];
      bV[s] = *(const bf16x8*)&Wv[roff];
    }
#pragma unroll
    for (int a = 0; a < 4; ++a) {
      bf16x8 af = *(const bf16x8*)&xL[(a * 16 + lo) * 136 + kt + hi * 8];
#pragma unroll
      for (int s = 0; s < 2; ++s) {
        aQ[a][s] = __builtin_amdgcn_mfma_f32_16x16x32_bf16(af, bQ[s], aQ[a][s], 0, 0, 0);
        aK[a][s] = __builtin_amdgcn_mfma_f32_16x16x32_bf16(af, bK[s], aK[a][s], 0, 0, 0);
        aV[a][s] = __builtin_amdgcn_mfma_f32_16x16x32_bf16(af, bV[s], aV[a][s], 0, 0, 0);
      }
    }
  }

  // ---- sigQ -> C-frag order: CF[b][it][dt][lane][r]
#pragma unroll
  for (int s = 0; s < 2; ++s) {
    int dt = (d0 >> 4) + s;
    float bb = bq[d0 + s * 16 + lo];
#pragma unroll
    for (int a = 0; a < 4; ++a) {
      int it = (tl0 >> 4) + a;
      us4 v;
#pragma unroll
      for (int r = 0; r < 4; ++r) {
        float q = aQ[a][s][r] + bb;
        v[r] = f2bf(1.f / (1.f + __expf(-q)));
      }
      ((us4*)SQ)[(((size_t)b * NIT + it) * 8 + dt) * 64 + lane] = v;
    }
  }

  // ---- eK/eKV -> B-frag order: BF[b][kt][dt][lane_f][c], c=(hi&1)*4+r
#pragma unroll
  for (int s = 0; s < 2; ++s) {
    int dt = (d0 >> 4) + s;
    float bbk = bk_[d0 + s * 16 + lo], bbv = bv[d0 + s * 16 + lo];
#pragma unroll
    for (int a = 0; a < 4; ++a) {
      int kt = (tl0 >> 5) + (a >> 1);
      int lane_f = ((a & 1) * 2 + (hi >> 1)) * 16 + lo;
      us4 vk, vv;
#pragma unroll
      for (int r = 0; r < 4; ++r) {
        int tg = g0 + a * 16 + hi * 4 + r;      // global key-token index
        int mk = mask[tg];
        float ek = mk ? __expf(aK[a][s][r] + bbk) : 0.f;
        float ekv = ek * (aV[a][s][r] + bbv);
        vk[r] = f2bf(ek);
        vv[r] = f2bf(ekv);
      }
      size_t q4 = ((((size_t)b * NKT + kt) * 8 + dt) * 64 + lane_f) * 2 + (hi & 1);
      ((us4*)BK)[q4] = vk;
      ((us4*)BV)[q4] = vv;
    }
  }
}

// ---------------------------------------------------------------------------
// aft_all: barrier-free main loop over fragment-packed operands.
// Block tile 128i x 128d (4 waves 2x2, wave 64i x 64d). K-step = one 32-j tile.
// Per step/wave: 4 A-frag + 8 B-frag coalesced us8 loads, 32 MFMA. No LDS.
// Epilogue: Y -> LDS -> Z = Y@Wp^T + bias -> masked row-max -> encoded atomicMax.
// ---------------------------------------------------------------------------
__global__ __launch_bounds__(256, 2) void aft_all(
    const unsigned short* __restrict__ AFd, const unsigned short* __restrict__ AFp,
    const unsigned short* __restrict__ SQd, const unsigned short* __restrict__ BKd,
    const unsigned short* __restrict__ BVd,
    const unsigned short* __restrict__ SQp, const unsigned short* __restrict__ BKp,
    const unsigned short* __restrict__ BVp,
    const int* __restrict__ smask, const int* __restrict__ pmask,
    const unsigned short* __restrict__ Wbf,
    const float* __restrict__ bpd, const float* __restrict__ bpp,
    unsigned int* __restrict__ outEnc) {
  __shared__ unsigned short yL[128 * 136];   // 34816 B, epilogue only

  const int blk = blockIdx.x;
  const unsigned short *AF, *BK, *BV, *SQ, *Wp;
  const float* bp;
  const int* msk;
  unsigned int* oEnc;
  int b, i0, NKT, NIT;
  if (blk < 128) {  // drug queries over protein keys; blk = itile*64 + b
    b = blk & 63; i0 = (blk >> 6) * 128; NKT = 32; NIT = 16;
    AF = AFd; BK = BKp; BV = BVp; SQ = SQd;
    Wp = Wbf + 6 * 16384; bp = bpd; msk = smask + b * 256 + i0; oEnc = outEnc;
  } else {          // protein queries over drug keys
    int k = blk - 128;
    b = k & 63; i0 = (k >> 6) * 128; NKT = 8; NIT = 64;
    AF = AFp; BK = BKd; BV = BVd; SQ = SQp;
    Wp = Wbf + 7 * 16384; bp = bpp; msk = pmask + b * 1024 + i0; oEnc = outEnc + 8192;
  }

  const int tid = threadIdx.x, lane = tid & 63, w = tid >> 6;
  const int lo = lane & 15, hi = lane >> 4;
  const int wi = (w >> 1) * 64, wd = (w & 1) * 64;
  const int it0 = (i0 + wi) >> 4;          // i-tile base (local to side)
  const int dt0 = wd >> 4;                 // d-tile base

  const unsigned short* BKb = BK + (size_t)b * NKT * 8 * 64 * 8;
  const unsigned short* BVb = BV + (size_t)b * NKT * 8 * 64 * 8;

  f32x4 aN[4][4], aD[4][4];
#pragma unroll
  for (int a = 0; a < 4; ++a)
#pragma unroll
    for (int n = 0; n < 4; ++n)
#pragma unroll
      for (int r = 0; r < 4; ++r) { aN[a][n][r] = 0.f; aD[a][n][r] = 0.f; }

#pragma unroll 2
  for (int kt = 0; kt < NKT; ++kt) {
    bf16x8 af[4];
#pragma unroll
    for (int a = 0; a < 4; ++a)
      af[a] = *(const bf16x8*)&AF[(((size_t)(it0 + a) * NKT + kt) * 64 + lane) * 8];
    bf16x8 bk[4], bv[4];
#pragma unroll
    for (int n = 0; n < 4; ++n) {
      size_t x = (((size_t)kt * 8 + dt0 + n) * 64 + lane) * 8;
      bk[n] = *(const bf16x8*)&BKb[x];
      bv[n] = *(const bf16x8*)&BVb[x];
    }
#pragma unroll
    for (int a = 0; a < 4; ++a)
#pragma unroll
      for (int n = 0; n < 4; ++n) {
        aN[a][n] = __builtin_amdgcn_mfma_f32_16x16x32_bf16(af[a], bv[n], aN[a][n], 0, 0, 0);
        aD[a][n] = __builtin_amdgcn_mfma_f32_16x16x32_bf16(af[a], bk[n], aD[a][n], 0, 0, 0);
      }
  }

  // ---- Y = sig(Q)*num/den -> LDS bf16 [128 i][136 stride]
#pragma unroll
  for (int a = 0; a < 4; ++a)
#pragma unroll
    for (int n = 0; n < 4; ++n) {
      us4 q = ((const us4*)SQ)[(((size_t)b * NIT + it0 + a) * 8 + dt0 + n) * 64 + lane];
      int iL = wi + a * 16 + hi * 4;
      int d = wd + n * 16 + lo;
#pragma unroll
      for (int r = 0; r < 4; ++r) {
        float y = bf2f(q[r]) * __fdividef(aN[a][n][r], aD[a][n][r]);
        yL[(iL + r) * 136 + d] = f2bf(y);
      }
    }
  __syncthreads();

  // ---- Z = Y @ Wp^T (K=128), bias, masked row-max, encoded atomicMax
  f32x4 aZ[4][4];
#pragma unroll
  for (int a = 0; a < 4; ++a)
#pragma unroll
    for (int n = 0; n < 4; ++n)
#pragma unroll
      for (int r = 0; r < 4; ++r) aZ[a][n][r] = 0.f;

#pragma unroll
  for (int kt = 0; kt < 128; kt += 32) {
    bf16x8 bw[4];
#pragma unroll
    for (int n = 0; n < 4; ++n)
      bw[n] = *(const bf16x8*)&Wp[(size_t)(wd + n * 16 + lo) * 128 + kt + hi * 8];
#pragma unroll
    for (int a = 0; a < 4; ++a) {
      bf16x8 af = *(const bf16x8*)&yL[(wi + a * 16 + lo) * 136 + kt + hi * 8];
#pragma unroll
      for (int n = 0; n < 4; ++n)
        aZ[a][n] = __builtin_amdgcn_mfma_f32_16x16x32_bf16(af, bw[n], aZ[a][n], 0, 0, 0);
    }
  }

#pragma unroll
  for (int n = 0; n < 4; ++n) {
    int d = wd + n * 16 + lo;
    float bb = bp[d];
    float m = NEGV;
#pragma unroll
    for (int a = 0; a < 4; ++a)
#pragma unroll
      for (int r = 0; r < 4; ++r) {
        int iL = wi + a * 16 + hi * 4 + r;
        float z = aZ[a][n][r] + bb;
        m = msk[iL] ? fmaxf(m, z) : m;
      }
    m = fmaxf(m, __shfl_xor(m, 16, 64));
    m = fmaxf(m, __shfl_xor(m, 32, 64));
    if (hi == 0) {
      unsigned bits = __float_as_uint(m);
      unsigned key = (bits & 0x80000000u) ? ~bits : (bits | 0x80000000u);
      atomicMax(&oEnc[b * 128 + d], key);
    }
  }
}

// ---------------------------------------------------------------------------
__global__ void out_decode(unsigned int* o) {
  int i = blockIdx.x * 256 + threadIdx.x;
  unsigned k = o[i];
  unsigned bits = (k & 0x80000000u) ? (k ^ 0x80000000u) : ~k;
  ((float*)o)[i] = __uint_as_float(bits);
}

// ---------------------------------------------------------------------------
extern "C" void kernel_launch(void* const* d_in, const int* in_sizes, int n_in,
                              void* d_out, int out_size, void* d_ws, size_t ws_size,
                              hipStream_t stream) {
  const float* smiles = (const float*)d_in[0];
  const float* prot   = (const float*)d_in[1];
  const int* smask = (const int*)d_in[2];
  const int* pmask = (const int*)d_in[3];
  const float* pos_bias = (const float*)d_in[4];
  const float* Wqd = (const float*)d_in[5];  const float* bqd = (const float*)d_in[6];
  const float* Wkp = (const float*)d_in[7];  const float* bkp = (const float*)d_in[8];
  const float* Wvp = (const float*)d_in[9];  const float* bvp = (const float*)d_in[10];
  const float* Wqp = (const float*)d_in[11]; const float* bqp = (const float*)d_in[12];
  const float* Wkd = (const float*)d_in[13]; const float* bkd = (const float*)d_in[14];
  const float* Wvd = (const float*)d_in[15]; const float* bvd = (const float*)d_in[16];
  const float* Wpd = (const float*)d_in[17]; const float* bpd = (const float*)d_in[18];
  const float* Wpp = (const float*)d_in[19]; const float* bpp = (const float*)d_in[20];

  // Workspace (unsigned short units)
  unsigned short* u = (unsigned short*)d_ws;
  unsigned short* BKp_  = u;                  // 64*32*8*512 = 8,388,608
  unsigned short* BVp_  = BKp_ + 8388608;     // 8,388,608
  unsigned short* BKd_  = BVp_ + 8388608;     // 64*8*8*512 = 2,097,152
  unsigned short* BVd_  = BKd_ + 2097152;     // 2,097,152
  unsigned short* SQd_  = BVd_ + 2097152;     // 64*16*8*256 = 2,097,152
  unsigned short* SQp_  = SQd_ + 2097152;     // 64*64*8*256 = 8,388,608
  unsigned short* epb_  = SQp_ + 8388608;     // 262,144
  unsigned short* epbT_ = epb_ + 262144;      // 262,144
  unsigned short* AFd_  = epbT_ + 262144;     // 16*32*512 = 262,144
  unsigned short* AFp_  = AFd_ + 262144;      // 64*8*512 = 262,144
  unsigned short* Wbf   = AFp_ + 262144;      // 8 * 16,384
  // Wbf order: [Wqd, Wkd, Wvd, Wqp, Wkp, Wvp, Wpd, Wpp]

  dim3 blk(256);

  prep_kernel<<<448, blk, 0, stream>>>(Wqd, Wkd, Wvd, Wqp, Wkp, Wvp, Wpd, Wpp,
                                       Wbf, pos_bias, epb_, epbT_,
                                       (unsigned int*)d_out);

  proj3_all<<<1536, blk, 0, stream>>>(smiles, prot, smask, pmask, Wbf,
                                      bqd, bkd, bvd, bqp, bkp, bvp,
                                      epb_, epbT_, AFd_, AFp_,
                                      SQd_, BKd_, BVd_, SQp_, BKp_, BVp_);

  aft_all<<<640, blk, 0, stream>>>(AFd_, AFp_, SQd_, BKd_, BVd_,
                                   SQp_, BKp_, BVp_, smask, pmask, Wbf,
                                   bpd, bpp, (unsigned int*)d_out);

  out_decode<<<64, blk, 0, stream>>>((unsigned int*)d_out);
}